// Round 15
// baseline (426.366 us; speedup 1.0000x reference)
//
#include <hip/hip_runtime.h>

#define BB 4
#define NN 4096
#define KK 16

typedef unsigned short u16;
typedef unsigned int   u32;
typedef unsigned long long u64;

typedef __attribute__((ext_vector_type(8))) short bf16x8;
typedef __attribute__((ext_vector_type(4))) float f32x4;

__device__ __forceinline__ float b2f(u16 x){ return __uint_as_float(((u32)x) << 16); }
__device__ __forceinline__ u16 f2b(float f){
    u32 u = __float_as_uint(f);
    u32 r = (u + 0x7FFFu + ((u >> 16) & 1u)) >> 16;   // RNE
    return (u16)r;
}
__device__ __forceinline__ u32 fmap(float f){
    u32 u = __float_as_uint(f);
    return (u & 0x80000000u) ? ~u : (u | 0x80000000u);
}
__device__ __forceinline__ float funmap(u32 u){
    u32 v = (u & 0x80000000u) ? (u ^ 0x80000000u) : ~u;
    return __uint_as_float(v);
}

// ---------------- input normalization (runtime dtype detect: f32 vs bf16) ----
#define N_ARR 27
__device__ const int ASZ[N_ARR] = {
    49152, 384, 64, 64, 64, 8192, 128, 128, 128, 32768, 256,
    66304, 256, 256, 256, 131072, 512, 512, 512, 524288, 1024,
    655360, 512, 131072, 256, 4096, 16 };
__device__ const int AOFF[N_ARR] = {
    0, 49152, 49536, 49600, 49664, 49728, 57920, 58048, 58176, 58304, 91072,
    91328, 157632, 157888, 158144, 158400, 289472, 289984, 290496, 291008, 815296,
    816320, 1471680, 1472192, 1603264, 1603520, 1607616 };

struct Ptrs { const void* p[N_ARR]; };

#define O_POS 0
#define O_CW1 49152
#define O_CB1 49536
#define O_CG1 49600
#define O_CS1 49664
#define O_CB2 57920
#define O_CG2 58048
#define O_CS2 58176
#define O_CB3 91072
#define O_SW1 91328
#define O_SB1 157632
#define O_SG1 157888
#define O_SS1 158144
#define O_SB2 289472
#define O_SG2 289984
#define O_SS2 290496
#define O_SB3 815296
#define O_PW1 816320
#define O_PB1 1471680
#define O_PW2 1472192
#define O_PB2 1603264
#define O_PW3 1603520
#define O_PB3 1607616

__global__ void detect_kernel(const u16* __restrict__ pos_u16, u32* __restrict__ flag){
    __shared__ int cnt;
    if (threadIdx.x == 0) cnt = 0;
    __syncthreads();
    int c = 0;
    #pragma unroll
    for (int s = 0; s < 4; ++s){
        u16 u = pos_u16[2*(threadIdx.x*4 + s)];
        int e = (u >> 7) & 0xFF;
        c += (e >= 0x68 && e <= 0x82) ? 1 : 0;
    }
    atomicAdd(&cnt, c);
    __syncthreads();
    if (threadIdx.x == 0) *flag = (cnt >= 512) ? 1u : 0u;   // 1 = bf16 inputs
}

// Pack weight matrix (row-major KxN) from SOURCE (f32 or bf16) into MFMA B-frag order:
// dst[((ks*N + n)*4 + lg)*8 + i] = bf16(W[(ks*32 + lg*8 + i)*N + n])
__device__ __forceinline__ void pack_one_src(const void* __restrict__ src, bool isbf,
                                             u16* __restrict__ dst, int tot, int log2n,
                                             int g, int T){
    const int nmask = (1 << log2n) - 1;
    for (int id = g; id < tot; id += T){
        int i = id & 7, lg = (id >> 3) & 3;
        int rest = id >> 5;
        int n = rest & nmask;
        int ks = rest >> log2n;
        int si = (ks*32 + lg*8 + i) << log2n | n;
        dst[id] = isbf ? ((const u16*)src)[si] : f2b(((const float*)src)[si]);
    }
}

// convert needed arrays to f32, build SoA positions, pack the 5 MFMA weight matrices
__global__ __launch_bounds__(256) void prep_kernel(Ptrs pt, const u32* __restrict__ flagp,
        float* __restrict__ dst, float* __restrict__ psoa,
        u16* __restrict__ wp2, u16* __restrict__ wp3,
        u16* __restrict__ swp1, u16* __restrict__ swp2, u16* __restrict__ swp3){
    const bool isbf = (*flagp != 0);
    const int T = gridDim.x * 256;
    const int g = blockIdx.x * 256 + threadIdx.x;
    #pragma unroll
    for (int a = 0; a < N_ARR; ++a){
        if (a == 5 || a == 9 || a == 15 || a == 19) continue;   // only packed copies used
        const int sz = ASZ[a], off = AOFF[a];
        if (isbf){
            const u16* s = (const u16*)pt.p[a];
            for (int i = g; i < sz; i += T) dst[off + i] = b2f(s[i]);
        } else {
            const float* s = (const float*)pt.p[a];
            for (int i = g; i < sz; i += T) dst[off + i] = s[i];
        }
    }
    for (int i = g; i < BB*NN; i += T){
        float x, y, z;
        if (isbf){
            const u16* s = (const u16*)pt.p[0];
            x = b2f(s[3*i]); y = b2f(s[3*i+1]); z = b2f(s[3*i+2]);
        } else {
            const float* s = (const float*)pt.p[0];
            x = s[3*i]; y = s[3*i+1]; z = s[3*i+2];
        }
        psoa[i] = x; psoa[BB*NN + i] = y; psoa[2*BB*NN + i] = z;
    }
    pack_one_src(pt.p[5],  isbf, wp2,    8192,  7, g, T);
    pack_one_src(pt.p[9],  isbf, wp3,   32768,  8, g, T);
    pack_one_src(pt.p[11], isbf, swp1,  65536,  8, g, T);   // first 256 K-rows of sw1
    pack_one_src(pt.p[15], isbf, swp2, 131072,  9, g, T);
    pack_one_src(pt.p[19], isbf, swp3, 524288, 10, g, T);
}

// ---------------------------------------------------------------- sort by x (two stages)
__global__ __launch_bounds__(1024) void sort1_kernel(const float* __restrict__ psoa,
                                                     u64* __restrict__ keys){
    __shared__ u64 s[2048];   // 16 KB
    const int half = blockIdx.x;       // 0..7
    const int b    = half >> 1;
    const int base = (half & 1) << 11; // 0 or 2048
    const float* px = psoa + b*NN;
    const int tid = threadIdx.x;
    for (int i = tid; i < 2048; i += 1024)
        s[i] = (((u64)fmap(px[base + i])) << 32) | (u32)(base + i);
    __syncthreads();
    for (int ksz = 2; ksz <= 2048; ksz <<= 1){
        for (int jj = ksz >> 1; jj > 0; jj >>= 1){
            int t = tid;
            int i  = ((t & ~(jj-1)) << 1) | (t & (jj-1));
            int ix = i | jj;
            u64 a = s[i], v = s[ix];
            bool up = (((base + i) & ksz) == 0);
            if ((a > v) == up){ s[i] = v; s[ix] = a; }
            __syncthreads();
        }
    }
    for (int i = tid; i < 2048; i += 1024) keys[b*NN + base + i] = s[i];
}

__global__ __launch_bounds__(1024) void sort2_kernel(const u64* __restrict__ keys,
        const float* __restrict__ psoa,
        float* __restrict__ xs, float* __restrict__ ys, float* __restrict__ zs,
        int* __restrict__ sidx){
    __shared__ u64 s[NN];   // 32 KB
    const int b = blockIdx.x;
    const int tid = threadIdx.x;
    for (int i = tid; i < NN; i += 1024) s[i] = keys[b*NN + i];
    __syncthreads();
    for (int jj = NN >> 1; jj > 0; jj >>= 1){
        for (int t = tid; t < NN/2; t += 1024){
            int i  = ((t & ~(jj-1)) << 1) | (t & (jj-1));
            int ix = i | jj;
            u64 a = s[i], v = s[ix];
            if (a > v){ s[i] = v; s[ix] = a; }   // ksz=4096: ascending everywhere
        }
        __syncthreads();
    }
    const float* py = psoa + BB*NN;
    const float* pz = psoa + 2*BB*NN;
    for (int r = tid; r < NN; r += 1024){
        u64 kv = s[r];
        int oi = (int)(u32)(kv & 0xFFFFFFFFu);
        xs[b*NN + r] = funmap((u32)(kv >> 32));
        ys[b*NN + r] = py[b*NN + oi];
        zs[b*NN + r] = pz[b*NN + oi];
        sidx[b*NN + r] = oi;
    }
}

// ---------------------------------------------------------------- kNN (+ degree count)
// Sorted-axis pruned, exact. Superstep of 8 iterations: 24 candidate loads batched
// up-front (one wait); push/refine order per k unchanged (bit-identical selection);
// termination checked once per superstep (superset, exact).
#define QCAP 192
__device__ __forceinline__ void refine16(u64* __restrict__ buf, int& cnt, float& tau, int lane){
    u64 loc[3];
    #pragma unroll
    for (int q = 0; q < 3; ++q){
        int p = lane + (q << 6);
        loc[q] = (p < cnt) ? buf[p] : ~0ull;
    }
    u64 m = ~0ull;
    #pragma unroll
    for (int r = 0; r < KK; ++r){
        m = loc[0];
        m = loc[1] < m ? loc[1] : m;
        m = loc[2] < m ? loc[2] : m;
        #pragma unroll
        for (int off = 32; off > 0; off >>= 1){
            u64 o = __shfl_xor(m, off);
            m = o < m ? o : m;
        }
        if (lane == r) buf[r] = m;
        #pragma unroll
        for (int q = 0; q < 3; ++q) if (loc[q] == m) loc[q] = ~0ull;
    }
    cnt = KK;
    tau = __uint_as_float((u32)(m >> 32));   // d2 of the 16th smallest
}

__global__ __launch_bounds__(512) void knn_kernel(
        const float* __restrict__ xs, const float* __restrict__ ys,
        const float* __restrict__ zs, const int* __restrict__ sidx,
        int* __restrict__ knn_out, u32* __restrict__ deg){
    __shared__ __align__(16) u64 kbuf[16*QCAP];  // 24 KB
    const int b  = blockIdx.x >> 8;              // 256 blocks per batch
    const int r0 = (blockIdx.x & 255) << 4;      // 16 sorted-rank queries per block
    const float* X = xs + b*NN;
    const float* Y = ys + b*NN;
    const float* Z = zs + b*NN;
    const int*   S = sidx + b*NN;
    const int tid = threadIdx.x;
    const int lane = tid & 63;
    const int wv = tid >> 6;                     // 0..7
    const int rA = r0 + wv*2, rB = rA + 1;
    const float axq = X[rA], ayq = Y[rA], azq = Z[rA];
    const float bxq = X[rB], byq = Y[rB], bzq = Z[rB];
    u64* bufA = kbuf + (wv*2)*QCAP;
    u64* bufB = bufA + QCAP;

    float tauA = 3.0e38f, tauB = 3.0e38f;
    int cntA = 0, cntB = 0;
    for (int k0 = 0; k0 < 128; k0 += 8){
        // batched candidate loads for 8 sub-iterations (24 independent loads, one wait)
        float cxv[8], cyv[8], czv[8];
        #pragma unroll
        for (int c = 0; c < 8; ++c){
            int k = k0 + c;
            int j = (lane < 32) ? (rA - 1 - (k << 5) - lane)
                                : (rA + (k << 5) + (lane - 32));
            int ja = ((u32)j < (u32)NN) ? j : rA;
            cxv[c] = X[ja]; cyv[c] = Y[ja]; czv[c] = Z[ja];
        }
        #pragma unroll
        for (int c = 0; c < 8; ++c){
            int k = k0 + c;
            int j = (lane < 32) ? (rA - 1 - (k << 5) - lane)
                                : (rA + (k << 5) + (lane - 32));
            bool inr = ((u32)j < (u32)NN);
            int ja = inr ? j : rA;
            float cx = cxv[c], cy = cyv[c], cz = czv[c];
            float dxA = axq - cx, dyA = ayq - cy, dzA = azq - cz;
            float d2A = __fadd_rn(__fadd_rn(__fmul_rn(dxA,dxA), __fmul_rn(dyA,dyA)), __fmul_rn(dzA,dzA));
            float dxB = bxq - cx, dyB = byq - cy, dzB = bzq - cz;
            float d2B = __fadd_rn(__fadd_rn(__fmul_rn(dxB,dxB), __fmul_rn(dyB,dyB)), __fmul_rn(dzB,dzB));
            bool pA = inr && (d2A <= tauA);
            bool pB = inr && (d2B <= tauB);
            u64 balA = __ballot(pA);
            u64 balB = __ballot(pB);
            int sorig = 0;
            if (balA | balB) sorig = S[ja];      // wave-uniform: load only when pushing
            if (balA){
                int nins = __popcll(balA);
                if (cntA + nins > QCAP) refine16(bufA, cntA, tauA, lane);
                if (pA){
                    int ofs = __popcll(balA & ((1ull << lane) - 1ull));
                    bufA[cntA + ofs] = (((u64)__float_as_uint(d2A)) << 32) | (u32)sorig;
                }
                cntA += nins;
            }
            if (balB){
                int nins = __popcll(balB);
                if (cntB + nins > QCAP) refine16(bufB, cntB, tauB, lane);
                if (pB){
                    int ofs = __popcll(balB & ((1ull << lane) - 1ull));
                    bufB[cntB + ofs] = (((u64)__float_as_uint(d2B)) << 32) | (u32)sorig;
                }
                cntB += nins;
            }
        }
        // termination from boundary lanes of the last sub-iteration
        // (lane31 = leftmost examined rank, lane63 = rightmost examined rank)
        float xL = __shfl(cxv[7], 31);
        float xR = __shfl(cxv[7], 63);
        const int k = k0 + 7;
        bool lex = (rA - ((k + 1) << 5) - 1) < 0;    // left side exhausted
        bool rex = (rA + ((k + 1) << 5)) >= NN;      // right side exhausted
        float dLa = axq - xL, dRa = xR - axq;
        float dLb = bxq - xL, dRb = xR - bxq;
        bool ldone = lex || (dLa*dLa > tauA && dLb*dLb > tauB);
        bool rdone = rex || (dRa*dRa > tauA && dRb*dRb > tauB);
        if (ldone && rdone) break;
    }
    refine16(bufA, cntA, tauA, lane);
    refine16(bufB, cntB, tauB, lane);
    const int origA = S[rA], origB = S[rB];
    if (lane < KK){
        u64 kA = bufA[lane];
        int jA = (int)(u32)(kA & 0xFFFFFFFFu);
        knn_out[((size_t)(b*NN + origA))*KK + lane] = jA;
        atomicAdd(deg + (b << 12) + jA, 1u);
        u64 kB = bufB[lane];
        int jB = (int)(u32)(kB & 0xFFFFFFFFu);
        knn_out[((size_t)(b*NN + origB))*KK + lane] = jB;
        atomicAdd(deg + (b << 12) + jB, 1u);
    }
}

// ---------------------------------------------------------------- CSR build
__global__ __launch_bounds__(1024) void scan_kernel(const u32* __restrict__ deg,
                                                    int* __restrict__ rowstart, u32* __restrict__ cursor){
    __shared__ int lsum[1024];
    const int tid = threadIdx.x;
    const int base = tid * 16;
    int loc[16]; int s = 0;
    #pragma unroll
    for (int q = 0; q < 16; ++q){ loc[q] = (int)deg[base+q]; s += loc[q]; }
    lsum[tid] = s;
    __syncthreads();
    int acc = s;
    for (int ofs = 1; ofs < 1024; ofs <<= 1){
        int t = (tid >= ofs) ? lsum[tid-ofs] : 0;
        __syncthreads();
        acc += t; lsum[tid] = acc;
        __syncthreads();
    }
    int excl = acc - s;
    #pragma unroll
    for (int q = 0; q < 16; ++q){
        rowstart[base+q] = excl; cursor[base+q] = (u32)excl; excl += loc[q];
    }
    if (tid == 1023) rowstart[16384] = excl;
}

__global__ __launch_bounds__(256) void fill_kernel(const int* __restrict__ knn,
                                                   u32* __restrict__ cursor, int* __restrict__ csr){
    int e = blockIdx.x*256 + threadIdx.x;
    int b = e >> 16;
    int t = (b << 12) + knn[e];
    u32 pos = atomicAdd(cursor + t, 1u);
    csr[pos] = e;
}

// ---------------------------------------------------------------- LDS fragment helpers
__device__ __forceinline__ bf16x8 ldfrag(const u16* h, int row, int kofs, int rowstride){
    u32 byte = (u32)((row*rowstride + kofs)*2) ^ (u32)((row & 7) << 4);
    return *(const bf16x8*)((const char*)h + byte);
}
__device__ __forceinline__ void st16(u16* h, int row, int col, int rowstride, float v){
    u32 byte = (u32)((row*rowstride + col)*2) ^ (u32)((row & 7) << 4);
    *(u16*)((char*)h + byte) = f2b(v);
}

// ---------------------------------------------------------------- edge MLP (MFMA) + segment max
__global__ __launch_bounds__(256, 2) void edge_kernel(
    const float* __restrict__ conv, const int* __restrict__ knn,
    const int* __restrict__ rowstart, const int* __restrict__ csr,
    const u16* __restrict__ wp2, const u16* __restrict__ wp3,
    u16* __restrict__ xh)
{
    __shared__ float in6[6][64];
    __shared__ int   lts[64];
    __shared__ int   rs_l[17];
    __shared__ float scw1[384];
    __shared__ float sc1[64], sh1[64];
    __shared__ __align__(16) u16 h1s[64*64];    // 8 KB swizzled [edge][ch]
    __shared__ __align__(16) u16 h2s[64*128];   // 16 KB swizzled
    __shared__ u32 lsx[16*256];                 // 16 KB fmap-max accumulator [target][ch]

    const float* posf = conv + O_POS;
    const float* cb1 = conv + O_CB1; const float* cg1 = conv + O_CG1; const float* cs1 = conv + O_CS1;

    const int tid = threadIdx.x;
    const int w   = tid >> 6;
    const int l   = tid & 63;
    const int t0  = blockIdx.x << 4;
    const int b   = t0 >> 12;

    if (tid < 64){ float g1 = cg1[tid]; sc1[tid]=g1; sh1[tid]=cb1[tid]*g1 + cs1[tid]; }
    if (tid < 17) rs_l[tid] = rowstart[t0 + tid];
    for (int u = tid; u < 384; u += 256) scw1[u] = conv[O_CW1 + u];
    #pragma unroll
    for (int q = 0; q < 16; ++q) lsx[q*256 + tid] = 0u;   // fmap identity (< any real value)

    const int lr = l & 15, lg = l >> 4;
    const int colb2 = w << 5;          // layer-2 cols [w*32, +32)
    const int colb3 = w << 6;          // layer-3 cols [w*64, +64)

    float sc2v[2], sh2v[2], bs3v[4];
    #pragma unroll
    for (int nt = 0; nt < 2; ++nt){
        int c = colb2 + nt*16 + lr;
        float g2 = conv[O_CG2 + c];
        sc2v[nt] = g2; sh2v[nt] = conv[O_CB2 + c]*g2 + conv[O_CS2 + c];
    }
    #pragma unroll
    for (int nt = 0; nt < 4; ++nt) bs3v[nt] = conv[O_CB3 + colb3 + nt*16 + lr];

    __syncthreads();
    const int segstart = rs_l[0], segend = rs_l[16];
    const int nchunk = (segend - segstart + 63) >> 6;

    int curl = -1;
    float run[4];
    #pragma unroll
    for (int nt = 0; nt < 4; ++nt) run[nt] = 0.f;

    for (int ch = 0; ch < nchunk; ++ch){
        __syncthreads();   // prev chunk's lts/in6/LDS fully consumed
        if (tid < 64){
            int gpos = segstart + (ch << 6) + tid;
            int lt = -1;
            float ax=0,ay=0,az=0,dx=0,dy=0,dz=0;
            if (gpos < segend){
                lt = 0;
                #pragma unroll
                for (int q = 1; q < 16; ++q) lt += (gpos >= rs_l[q]) ? 1 : 0;
                int e = csr[gpos];
                int i = (e >> 4) & (NN - 1);
                int j = knn[e];
                const float* pi = posf + ((size_t)(b*NN + i))*3;
                const float* pj = posf + ((size_t)(b*NN + j))*3;
                ax = pi[0]; ay = pi[1]; az = pi[2];
                dx = ax - pj[0]; dy = ay - pj[1]; dz = az - pj[2];
            }
            lts[tid] = lt;
            in6[0][tid]=ax; in6[1][tid]=ay; in6[2][tid]=az;
            in6[3][tid]=dx; in6[4][tid]=dy; in6[5][tid]=dz;
        }
        __syncthreads();

        { // layer 1 (VALU, K=6): thread -> edge tid&63, channels (tid>>6)*16..+15
            const int e = tid & 63, c0g = (tid >> 6) << 4;
            float a0=in6[0][e], a1=in6[1][e], a2=in6[2][e],
                  a3=in6[3][e], a4=in6[4][e], a5=in6[5][e];
            u32 pk[8];
            #pragma unroll
            for (int ci = 0; ci < 16; ++ci){
                int cc = c0g + ci;
                float acc = a0*scw1[cc]     + a1*scw1[64+cc]  + a2*scw1[128+cc]
                          + a3*scw1[192+cc] + a4*scw1[256+cc] + a5*scw1[320+cc];
                float v = fmaxf(acc*sc1[cc] + sh1[cc], 0.f);
                u32 h = (u32)f2b(v);
                if (ci & 1) pk[ci >> 1] |= h << 16; else pk[ci >> 1] = h;
            }
            u32 base = (u32)(e*128 + c0g*2);
            u32 swz  = (u32)((e & 7) << 4);
            *(uint4*)((char*)h1s + (base ^ swz))        = make_uint4(pk[0],pk[1],pk[2],pk[3]);
            *(uint4*)((char*)h1s + ((base + 16) ^ swz)) = make_uint4(pk[4],pk[5],pk[6],pk[7]);
        }
        __syncthreads();

        { // layer 2 (MFMA): M=64, N=128 (wave: 32 cols), K=64; B streamed
            f32x4 acc2[4][2];
            #pragma unroll
            for (int mt = 0; mt < 4; ++mt)
                #pragma unroll
                for (int nt = 0; nt < 2; ++nt) acc2[mt][nt] = (f32x4){0.f,0.f,0.f,0.f};
            #pragma unroll
            for (int ks = 0; ks < 2; ++ks){
                bf16x8 bf[2];
                #pragma unroll
                for (int nt = 0; nt < 2; ++nt)
                    bf[nt] = *(const bf16x8*)(wp2 + (((ks*128 + colb2 + nt*16 + lr) << 2) + lg)*8);
                #pragma unroll
                for (int mt = 0; mt < 4; ++mt){
                    bf16x8 a = ldfrag(h1s, mt*16 + lr, ks*32 + lg*8, 64);
                    #pragma unroll
                    for (int nt = 0; nt < 2; ++nt)
                        acc2[mt][nt] = __builtin_amdgcn_mfma_f32_16x16x32_bf16(a, bf[nt], acc2[mt][nt], 0, 0, 0);
                }
            }
            #pragma unroll
            for (int mt = 0; mt < 4; ++mt)
                #pragma unroll
                for (int nt = 0; nt < 2; ++nt)
                    #pragma unroll
                    for (int r = 0; r < 4; ++r){
                        int row = mt*16 + lg*4 + r;
                        float v = fmaxf(acc2[mt][nt][r]*sc2v[nt] + sh2v[nt], 0.f);
                        st16(h2s, row, colb2 + nt*16 + lr, 128, v);
                    }
        }
        __syncthreads();

        { // layer 3 (MFMA): M=64, N=256 (wave: 64 cols), K=128; B streamed;
          // segmented max flushed straight from the accumulator into lsx
            f32x4 acc3[4][4];
            #pragma unroll
            for (int mt = 0; mt < 4; ++mt)
                #pragma unroll
                for (int nt = 0; nt < 4; ++nt) acc3[mt][nt] = (f32x4){0.f,0.f,0.f,0.f};
            #pragma unroll
            for (int ks = 0; ks < 4; ++ks){
                bf16x8 bf[4];
                #pragma unroll
                for (int nt = 0; nt < 4; ++nt)
                    bf[nt] = *(const bf16x8*)(wp3 + (((ks*256 + colb3 + nt*16 + lr) << 2) + lg)*8);
                #pragma unroll
                for (int mt = 0; mt < 4; ++mt){
                    bf16x8 a = ldfrag(h2s, mt*16 + lr, ks*32 + lg*8, 128);
                    #pragma unroll
                    for (int nt = 0; nt < 4; ++nt)
                        acc3[mt][nt] = __builtin_amdgcn_mfma_f32_16x16x32_bf16(a, bf[nt], acc3[mt][nt], 0, 0, 0);
                }
            }
            // per-lane run-length segmented max (rows ascend per lane; labels sorted)
            #pragma unroll
            for (int mt = 0; mt < 4; ++mt)
                #pragma unroll
                for (int r = 0; r < 4; ++r){
                    int row = mt*16 + lg*4 + r;
                    int lt = lts[row];
                    if (lt != curl){
                        if (curl >= 0){
                            #pragma unroll
                            for (int nt = 0; nt < 4; ++nt)
                                atomicMax(&lsx[curl*256 + colb3 + nt*16 + lr], fmap(run[nt]));
                        }
                        curl = lt;
                        #pragma unroll
                        for (int nt = 0; nt < 4; ++nt) run[nt] = acc3[mt][nt][r] + bs3v[nt];
                    } else {
                        #pragma unroll
                        for (int nt = 0; nt < 4; ++nt) run[nt] = fmaxf(run[nt], acc3[mt][nt][r] + bs3v[nt]);
                    }
                }
        }
    }
    if (curl >= 0){
        #pragma unroll
        for (int nt = 0; nt < 4; ++nt)
            atomicMax(&lsx[curl*256 + colb3 + nt*16 + lr], fmap(run[nt]));
    }
    __syncthreads();
    #pragma unroll
    for (int q = 0; q < 16; ++q)
        xh[((size_t)(t0+q))*256 + tid] = f2b(funmap(lsx[q*256 + tid]));
}

// ---------------------------------------------------------------- GlobalSA MLP (MFMA) + scene max
// 16 points/block, 1024 blocks (4 blocks/CU) for wave-level latency hiding.
__global__ __launch_bounds__(256, 4) void sa_kernel(
    const float* __restrict__ conv, const u16* __restrict__ xh,
    const u16* __restrict__ swp1, const u16* __restrict__ swp2, const u16* __restrict__ swp3,
    u32* __restrict__ scene_map)
{
    __shared__ __align__(16) u16 h1s[16*256];   // 8 KB
    __shared__ __align__(16) u16 h2s[16*512];   // 16 KB
    __shared__ float spw[3][256];
    __shared__ float spx[16], spy[16], spz[16];

    const int tid = threadIdx.x;
    const int w   = tid >> 6;
    const int l   = tid & 63;
    const int lr  = l & 15, lg = l >> 4;
    const int b   = blockIdx.x >> 8;
    const int n0  = (blockIdx.x & 255) << 4;
    const u16* xrow = xh + ((size_t)(b*NN + n0))*256;

    if (tid < 48){
        int p = tid & 15, d = tid >> 4;
        float v = conv[O_POS + ((size_t)(b*NN + n0 + p))*3 + d];
        if (d == 0) spx[p] = v; else if (d == 1) spy[p] = v; else spz[p] = v;
    }
    for (int u = tid; u < 768; u += 256)
        spw[u >> 8][u & 255] = conv[O_SW1 + (256 + (u >> 8))*256 + (u & 255)];
    __syncthreads();

    { // s1: 259 -> 256 ; wave cols [w*64, +64); A from global xh (rows 0..15)
        const int c0 = w << 6;
        float sc1v[4], sh1v[4];
        #pragma unroll
        for (int nt = 0; nt < 4; ++nt){
            int cc = c0 + nt*16 + lr;
            float g = conv[O_SG1 + cc];
            sc1v[nt] = g; sh1v[nt] = conv[O_SB1 + cc]*g + conv[O_SS1 + cc];
        }
        f32x4 acc[4];
        #pragma unroll
        for (int nt = 0; nt < 4; ++nt)
            #pragma unroll
            for (int r = 0; r < 4; ++r){
                int row = lg*4 + r;
                int cc  = c0 + nt*16 + lr;
                acc[nt][r] = spx[row]*spw[0][cc] + spy[row]*spw[1][cc] + spz[row]*spw[2][cc];
            }
        #pragma unroll
        for (int ks = 0; ks < 8; ++ks){
            bf16x8 bf[4];
            #pragma unroll
            for (int nt = 0; nt < 4; ++nt)
                bf[nt] = *(const bf16x8*)(swp1 + (((ks*256 + c0 + nt*16 + lr) << 2) + lg)*8);
            bf16x8 a = *(const bf16x8*)(xrow + lr*256 + ks*32 + lg*8);
            #pragma unroll
            for (int nt = 0; nt < 4; ++nt)
                acc[nt] = __builtin_amdgcn_mfma_f32_16x16x32_bf16(a, bf[nt], acc[nt], 0, 0, 0);
        }
        #pragma unroll
        for (int nt = 0; nt < 4; ++nt)
            #pragma unroll
            for (int r = 0; r < 4; ++r){
                int row = lg*4 + r;
                float v = fmaxf(acc[nt][r]*sc1v[nt] + sh1v[nt], 0.f);
                st16(h1s, row, c0 + nt*16 + lr, 256, v);
            }
    }
    __syncthreads();

    { // s2: 256 -> 512 ; wave cols [w*128, +128)
        const int c0 = w << 7;
        float sc2v[8], sh2v[8];
        #pragma unroll
        for (int nt = 0; nt < 8; ++nt){
            int cc = c0 + nt*16 + lr;
            float g = conv[O_SG2 + cc];
            sc2v[nt] = g; sh2v[nt] = conv[O_SB2 + cc]*g + conv[O_SS2 + cc];
        }
        f32x4 acc[8];
        #pragma unroll
        for (int nt = 0; nt < 8; ++nt) acc[nt] = (f32x4){0.f,0.f,0.f,0.f};
        #pragma unroll
        for (int ks = 0; ks < 8; ++ks){
            bf16x8 bf[8];
            #pragma unroll
            for (int nt = 0; nt < 8; ++nt)
                bf[nt] = *(const bf16x8*)(swp2 + (((ks*512 + c0 + nt*16 + lr) << 2) + lg)*8);
            bf16x8 a = ldfrag(h1s, lr, ks*32 + lg*8, 256);
            #pragma unroll
            for (int nt = 0; nt < 8; ++nt)
                acc[nt] = __builtin_amdgcn_mfma_f32_16x16x32_bf16(a, bf[nt], acc[nt], 0, 0, 0);
        }
        #pragma unroll
        for (int nt = 0; nt < 8; ++nt)
            #pragma unroll
            for (int r = 0; r < 4; ++r){
                int row = lg*4 + r;
                float v = fmaxf(acc[nt][r]*sc2v[nt] + sh2v[nt], 0.f);
                st16(h2s, row, c0 + nt*16 + lr, 512, v);
            }
    }
    __syncthreads();

    #pragma unroll
    for (int half = 0; half < 2; ++half){
        const int c0 = (half << 9) + (w << 7);
        f32x4 acc[8];
        #pragma unroll
        for (int nt = 0; nt < 8; ++nt) acc[nt] = (f32x4){0.f,0.f,0.f,0.f};
        #pragma unroll
        for (int ks = 0; ks < 16; ++ks){
            bf16x8 bf[8];
            #pragma unroll
            for (int nt = 0; nt < 8; ++nt)
                bf[nt] = *(const bf16x8*)(swp3 + (((ks*1024 + c0 + nt*16 + lr) << 2) + lg)*8);
            bf16x8 a = ldfrag(h2s, lr, ks*32 + lg*8, 512);
            #pragma unroll
            for (int nt = 0; nt < 8; ++nt)
                acc[nt] = __builtin_amdgcn_mfma_f32_16x16x32_bf16(a, bf[nt], acc[nt], 0, 0, 0);
        }
        #pragma unroll
        for (int nt = 0; nt < 8; ++nt){
            float v = fmaxf(fmaxf(acc[nt][0], acc[nt][1]), fmaxf(acc[nt][2], acc[nt][3]));
            v = fmaxf(v, __shfl_xor(v, 16));
            v = fmaxf(v, __shfl_xor(v, 32));
            if (lg == 0){
                int cc = c0 + nt*16 + lr;
                atomicMax(scene_map + (b << 10) + cc, fmap(v + conv[O_SB3 + cc]));
            }
        }
    }
}

// ---------------------------------------------------------------- head
__global__ __launch_bounds__(128) void head1_kernel(
    const float* __restrict__ conv,
    const u16* __restrict__ xh, const u32* __restrict__ scene_map, const int* __restrict__ qidx,
    float* __restrict__ h1out)
{
    __shared__ float ef[1280];
    __shared__ float psum[4][32];
    const float* pw1 = conv + O_PW1; const float* pb1 = conv + O_PB1;
    const int b  = blockIdx.x >> 4;
    const int c0 = (blockIdx.x & 15) << 5;
    const int tid = threadIdx.x;
    const int q = qidx[b];
    for (int u = tid; u < 1280; u += 128){
        float v;
        if (u < 256) v = b2f(xh[(((size_t)(b*NN + q)) << 8) + u]);
        else         v = funmap(scene_map[(b << 10) + (u - 256)]);
        ef[u] = v;
    }
    __syncthreads();
    const int c = c0 + (tid & 31);
    const int rc = tid >> 5;
    float acc = 0.f;
    for (int r = rc*320; r < rc*320 + 320; ++r) acc += ef[r] * pw1[r*512 + c];
    psum[rc][tid & 31] = acc;
    __syncthreads();
    if (tid < 32){
        float a = psum[0][tid] + psum[1][tid] + psum[2][tid] + psum[3][tid] + pb1[c0 + tid];
        h1out[(b << 9) + c0 + tid] = fmaxf(a, 0.f);
    }
}

__global__ __launch_bounds__(256) void head2_kernel(
    const float* __restrict__ conv, const float* __restrict__ h1in,
    const u32* __restrict__ flagp, void* __restrict__ outv)
{
    __shared__ float h1[4][512];
    __shared__ float h2[4][256];
    const float* pw2 = conv + O_PW2; const float* pb2 = conv + O_PB2;
    const float* pw3 = conv + O_PW3; const float* pb3 = conv + O_PB3;
    const int tid = threadIdx.x;
    for (int u = tid; u < 2048; u += 256) h1[u >> 9][u & 511] = h1in[u];
    __syncthreads();
    for (int o = tid; o < 1024; o += 256){
        int b = o >> 8, c = o & 255;
        float acc = pb2[c];
        for (int r = 0; r < 512; ++r) acc += h1[b][r] * pw2[r*256 + c];
        h2[b][c] = fmaxf(acc, 0.f);
    }
    __syncthreads();
    if (tid < 64){
        int b = tid >> 4, c = tid & 15;
        float acc = pb3[c];
        for (int r = 0; r < 256; ++r) acc += h2[b][r] * pw3[r*16 + c];
        if (*flagp) ((u16*)outv)[tid] = f2b(acc);
        else        ((float*)outv)[tid] = acc;
    }
}

// ---------------------------------------------------------------- launch
extern "C" void kernel_launch(void* const* d_in, const int* in_sizes, int n_in,
                              void* d_out, int out_size, void* d_ws, size_t ws_size,
                              hipStream_t stream){
    (void)in_sizes; (void)n_in; (void)out_size; (void)ws_size;
    const int* qidx = (const int*)d_in[1];

    char* ws = (char*)d_ws;
    u32*  flag      = (u32*)ws;                       // @0
    float* conv     = (float*)(ws + 1024);            // 6.43 MB f32
    u16*  wp2       = (u16*)(ws + 6432768);           // 16 KB  packed cw2
    u16*  wp3       = (u16*)(ws + 6449152);           // 64 KB  packed cw3
    u16*  swp1      = (u16*)(ws + 6514688);           // 128 KB packed sw1[0:256]
    u16*  swp2      = (u16*)(ws + 6645760);           // 256 KB packed sw2
    u16*  swp3      = (u16*)(ws + 6907904);           // 1 MB   packed sw3
    int*  knn       = (int*)(ws + 7956480);           // 1 MB
    u32*  deg       = (u32*)(ws + 9005056);           // 64 KB
    u32*  scene_map = (u32*)(ws + 9070592);           // 16 KB
    int*  rowstart  = (int*)(ws + 9086976);           // 64 KB + 4
    u32*  cursor    = (u32*)(ws + 9152576);           // 64 KB
    int*  csr       = (int*)(ws + 9218112);           // 1 MB
    u16*  xh        = (u16*)(ws + 10266688);          // 8 MB  [B*N, 256] bf16
    float* h1ws     = (float*)(ws + 18655296);        // 8 KB
    float* psoa     = (float*)(ws + 18663488);        // 192 KB SoA positions [3][B*N]
    float* xs       = (float*)(ws + 18860096);        // 64 KB sorted x
    float* ys       = (float*)(ws + 18925632);        // 64 KB sorted-permuted y
    float* zs       = (float*)(ws + 18991168);        // 64 KB sorted-permuted z
    int*   sidx     = (int*)(ws + 19056704);          // 64 KB sorted -> original idx
    u64*   keys     = (u64*)(ws + 19122240);          // 128 KB stage-1 sorted keys

    Ptrs pt;
    pt.p[0] = d_in[0];
    for (int k = 1; k < N_ARR; ++k) pt.p[k] = d_in[k + 1];

    hipMemsetAsync(ws + 9005056, 0, 81920, stream);   // deg + scene_map

    detect_kernel <<<1, 256, 0, stream>>>((const u16*)d_in[0], flag);
    prep_kernel   <<<512, 256, 0, stream>>>(pt, flag, conv, psoa, wp2, wp3, swp1, swp2, swp3);
    sort1_kernel  <<<BB*2, 1024, 0, stream>>>(psoa, keys);
    sort2_kernel  <<<BB, 1024, 0, stream>>>(keys, psoa, xs, ys, zs, sidx);
    knn_kernel <<<1024, 512, 0, stream>>>(xs, ys, zs, sidx, knn, deg);
    scan_kernel<<<1, 1024, 0, stream>>>(deg, rowstart, cursor);
    fill_kernel<<<1024, 256, 0, stream>>>(knn, cursor, csr);
    edge_kernel<<<1024, 256, 0, stream>>>(conv, knn, rowstart, csr, wp2, wp3, xh);
    sa_kernel  <<<BB*256, 256, 0, stream>>>(conv, xh, swp1, swp2, swp3, scene_map);
    head1_kernel<<<64, 128, 0, stream>>>(conv, xh, scene_map, qidx, h1ws);
    head2_kernel<<<1, 256, 0, stream>>>(conv, h1ws, flag, (void*)d_out);
}

// Round 16
// 369.447 us; speedup vs baseline: 1.1541x; 1.1541x over previous
//
#include <hip/hip_runtime.h>

#define BB 4
#define NN 4096
#define KK 16

typedef unsigned short u16;
typedef unsigned int   u32;
typedef unsigned long long u64;

typedef __attribute__((ext_vector_type(8))) short bf16x8;
typedef __attribute__((ext_vector_type(4))) float f32x4;

__device__ __forceinline__ float b2f(u16 x){ return __uint_as_float(((u32)x) << 16); }
__device__ __forceinline__ u16 f2b(float f){
    u32 u = __float_as_uint(f);
    u32 r = (u + 0x7FFFu + ((u >> 16) & 1u)) >> 16;   // RNE
    return (u16)r;
}
__device__ __forceinline__ u32 fmap(float f){
    u32 u = __float_as_uint(f);
    return (u & 0x80000000u) ? ~u : (u | 0x80000000u);
}
__device__ __forceinline__ float funmap(u32 u){
    u32 v = (u & 0x80000000u) ? (u ^ 0x80000000u) : ~u;
    return __uint_as_float(v);
}

// ---------------- input normalization (runtime dtype detect: f32 vs bf16) ----
#define N_ARR 27
__device__ const int ASZ[N_ARR] = {
    49152, 384, 64, 64, 64, 8192, 128, 128, 128, 32768, 256,
    66304, 256, 256, 256, 131072, 512, 512, 512, 524288, 1024,
    655360, 512, 131072, 256, 4096, 16 };
__device__ const int AOFF[N_ARR] = {
    0, 49152, 49536, 49600, 49664, 49728, 57920, 58048, 58176, 58304, 91072,
    91328, 157632, 157888, 158144, 158400, 289472, 289984, 290496, 291008, 815296,
    816320, 1471680, 1472192, 1603264, 1603520, 1607616 };

struct Ptrs { const void* p[N_ARR]; };

#define O_POS 0
#define O_CW1 49152
#define O_CB1 49536
#define O_CG1 49600
#define O_CS1 49664
#define O_CB2 57920
#define O_CG2 58048
#define O_CS2 58176
#define O_CB3 91072
#define O_SW1 91328
#define O_SB1 157632
#define O_SG1 157888
#define O_SS1 158144
#define O_SB2 289472
#define O_SG2 289984
#define O_SS2 290496
#define O_SB3 815296
#define O_PW1 816320
#define O_PB1 1471680
#define O_PW2 1472192
#define O_PB2 1603264
#define O_PW3 1603520
#define O_PB3 1607616

__global__ void detect_kernel(const u16* __restrict__ pos_u16, u32* __restrict__ flag){
    __shared__ int cnt;
    if (threadIdx.x == 0) cnt = 0;
    __syncthreads();
    int c = 0;
    #pragma unroll
    for (int s = 0; s < 4; ++s){
        u16 u = pos_u16[2*(threadIdx.x*4 + s)];
        int e = (u >> 7) & 0xFF;
        c += (e >= 0x68 && e <= 0x82) ? 1 : 0;
    }
    atomicAdd(&cnt, c);
    __syncthreads();
    if (threadIdx.x == 0) *flag = (cnt >= 512) ? 1u : 0u;   // 1 = bf16 inputs
}

// Pack weight matrix (row-major KxN) from SOURCE (f32 or bf16) into MFMA B-frag order:
// dst[((ks*N + n)*4 + lg)*8 + i] = bf16(W[(ks*32 + lg*8 + i)*N + n])
__device__ __forceinline__ void pack_one_src(const void* __restrict__ src, bool isbf,
                                             u16* __restrict__ dst, int tot, int log2n,
                                             int g, int T){
    const int nmask = (1 << log2n) - 1;
    for (int id = g; id < tot; id += T){
        int i = id & 7, lg = (id >> 3) & 3;
        int rest = id >> 5;
        int n = rest & nmask;
        int ks = rest >> log2n;
        int si = (ks*32 + lg*8 + i) << log2n | n;
        dst[id] = isbf ? ((const u16*)src)[si] : f2b(((const float*)src)[si]);
    }
}

// convert needed arrays to f32, build SoA positions, pack the 5 MFMA weight matrices
__global__ __launch_bounds__(256) void prep_kernel(Ptrs pt, const u32* __restrict__ flagp,
        float* __restrict__ dst, float* __restrict__ psoa,
        u16* __restrict__ wp2, u16* __restrict__ wp3,
        u16* __restrict__ swp1, u16* __restrict__ swp2, u16* __restrict__ swp3){
    const bool isbf = (*flagp != 0);
    const int T = gridDim.x * 256;
    const int g = blockIdx.x * 256 + threadIdx.x;
    #pragma unroll
    for (int a = 0; a < N_ARR; ++a){
        if (a == 5 || a == 9 || a == 15 || a == 19) continue;   // only packed copies used
        const int sz = ASZ[a], off = AOFF[a];
        if (isbf){
            const u16* s = (const u16*)pt.p[a];
            for (int i = g; i < sz; i += T) dst[off + i] = b2f(s[i]);
        } else {
            const float* s = (const float*)pt.p[a];
            for (int i = g; i < sz; i += T) dst[off + i] = s[i];
        }
    }
    for (int i = g; i < BB*NN; i += T){
        float x, y, z;
        if (isbf){
            const u16* s = (const u16*)pt.p[0];
            x = b2f(s[3*i]); y = b2f(s[3*i+1]); z = b2f(s[3*i+2]);
        } else {
            const float* s = (const float*)pt.p[0];
            x = s[3*i]; y = s[3*i+1]; z = s[3*i+2];
        }
        psoa[i] = x; psoa[BB*NN + i] = y; psoa[2*BB*NN + i] = z;
    }
    pack_one_src(pt.p[5],  isbf, wp2,    8192,  7, g, T);
    pack_one_src(pt.p[9],  isbf, wp3,   32768,  8, g, T);
    pack_one_src(pt.p[11], isbf, swp1,  65536,  8, g, T);   // first 256 K-rows of sw1
    pack_one_src(pt.p[15], isbf, swp2, 131072,  9, g, T);
    pack_one_src(pt.p[19], isbf, swp3, 524288, 10, g, T);
}

// ---------------------------------------------------------------- sort by x (two stages)
__global__ __launch_bounds__(1024) void sort1_kernel(const float* __restrict__ psoa,
                                                     u64* __restrict__ keys){
    __shared__ u64 s[2048];   // 16 KB
    const int half = blockIdx.x;       // 0..7
    const int b    = half >> 1;
    const int base = (half & 1) << 11; // 0 or 2048
    const float* px = psoa + b*NN;
    const int tid = threadIdx.x;
    for (int i = tid; i < 2048; i += 1024)
        s[i] = (((u64)fmap(px[base + i])) << 32) | (u32)(base + i);
    __syncthreads();
    for (int ksz = 2; ksz <= 2048; ksz <<= 1){
        for (int jj = ksz >> 1; jj > 0; jj >>= 1){
            int t = tid;
            int i  = ((t & ~(jj-1)) << 1) | (t & (jj-1));
            int ix = i | jj;
            u64 a = s[i], v = s[ix];
            bool up = (((base + i) & ksz) == 0);
            if ((a > v) == up){ s[i] = v; s[ix] = a; }
            __syncthreads();
        }
    }
    for (int i = tid; i < 2048; i += 1024) keys[b*NN + base + i] = s[i];
}

__global__ __launch_bounds__(1024) void sort2_kernel(const u64* __restrict__ keys,
        const float* __restrict__ psoa,
        float* __restrict__ xs, float* __restrict__ ys, float* __restrict__ zs,
        int* __restrict__ sidx){
    __shared__ u64 s[NN];   // 32 KB
    const int b = blockIdx.x;
    const int tid = threadIdx.x;
    for (int i = tid; i < NN; i += 1024) s[i] = keys[b*NN + i];
    __syncthreads();
    for (int jj = NN >> 1; jj > 0; jj >>= 1){
        for (int t = tid; t < NN/2; t += 1024){
            int i  = ((t & ~(jj-1)) << 1) | (t & (jj-1));
            int ix = i | jj;
            u64 a = s[i], v = s[ix];
            if (a > v){ s[i] = v; s[ix] = a; }   // ksz=4096: ascending everywhere
        }
        __syncthreads();
    }
    const float* py = psoa + BB*NN;
    const float* pz = psoa + 2*BB*NN;
    for (int r = tid; r < NN; r += 1024){
        u64 kv = s[r];
        int oi = (int)(u32)(kv & 0xFFFFFFFFu);
        xs[b*NN + r] = funmap((u32)(kv >> 32));
        ys[b*NN + r] = py[b*NN + oi];
        zs[b*NN + r] = pz[b*NN + oi];
        sidx[b*NN + r] = oi;
    }
}

// ---------------------------------------------------------------- kNN (+ degree count)
// Sorted-axis pruned, exact. Superstep of 4 iterations: 12 candidate loads batched
// up-front (one wait); push/refine order per k unchanged (bit-identical selection);
// termination checked once per superstep (superset, exact).
#define QCAP 192
__device__ __forceinline__ void refine16(u64* __restrict__ buf, int& cnt, float& tau, int lane){
    u64 loc[3];
    #pragma unroll
    for (int q = 0; q < 3; ++q){
        int p = lane + (q << 6);
        loc[q] = (p < cnt) ? buf[p] : ~0ull;
    }
    u64 m = ~0ull;
    #pragma unroll
    for (int r = 0; r < KK; ++r){
        m = loc[0];
        m = loc[1] < m ? loc[1] : m;
        m = loc[2] < m ? loc[2] : m;
        #pragma unroll
        for (int off = 32; off > 0; off >>= 1){
            u64 o = __shfl_xor(m, off);
            m = o < m ? o : m;
        }
        if (lane == r) buf[r] = m;
        #pragma unroll
        for (int q = 0; q < 3; ++q) if (loc[q] == m) loc[q] = ~0ull;
    }
    cnt = KK;
    tau = __uint_as_float((u32)(m >> 32));   // d2 of the 16th smallest
}

__global__ __launch_bounds__(512) void knn_kernel(
        const float* __restrict__ xs, const float* __restrict__ ys,
        const float* __restrict__ zs, const int* __restrict__ sidx,
        int* __restrict__ knn_out, u32* __restrict__ deg){
    __shared__ __align__(16) u64 kbuf[16*QCAP];  // 24 KB
    const int b  = blockIdx.x >> 8;              // 256 blocks per batch
    const int r0 = (blockIdx.x & 255) << 4;      // 16 sorted-rank queries per block
    const float* X = xs + b*NN;
    const float* Y = ys + b*NN;
    const float* Z = zs + b*NN;
    const int*   S = sidx + b*NN;
    const int tid = threadIdx.x;
    const int lane = tid & 63;
    const int wv = tid >> 6;                     // 0..7
    const int rA = r0 + wv*2, rB = rA + 1;
    const float axq = X[rA], ayq = Y[rA], azq = Z[rA];
    const float bxq = X[rB], byq = Y[rB], bzq = Z[rB];
    u64* bufA = kbuf + (wv*2)*QCAP;
    u64* bufB = bufA + QCAP;

    float tauA = 3.0e38f, tauB = 3.0e38f;
    int cntA = 0, cntB = 0;
    for (int k0 = 0; k0 < 128; k0 += 4){
        // batched candidate loads for 4 sub-iterations (12 independent loads, one wait)
        float cxv[4], cyv[4], czv[4];
        int jav[4]; bool inrv[4];
        #pragma unroll
        for (int c = 0; c < 4; ++c){
            int k = k0 + c;
            int j = (lane < 32) ? (rA - 1 - (k << 5) - lane)
                                : (rA + (k << 5) + (lane - 32));
            bool inr = ((u32)j < (u32)NN);
            int ja = inr ? j : rA;
            inrv[c] = inr; jav[c] = ja;
            cxv[c] = X[ja]; cyv[c] = Y[ja]; czv[c] = Z[ja];
        }
        #pragma unroll
        for (int c = 0; c < 4; ++c){
            float cx = cxv[c], cy = cyv[c], cz = czv[c];
            float dxA = axq - cx, dyA = ayq - cy, dzA = azq - cz;
            float d2A = __fadd_rn(__fadd_rn(__fmul_rn(dxA,dxA), __fmul_rn(dyA,dyA)), __fmul_rn(dzA,dzA));
            float dxB = bxq - cx, dyB = byq - cy, dzB = bzq - cz;
            float d2B = __fadd_rn(__fadd_rn(__fmul_rn(dxB,dxB), __fmul_rn(dyB,dyB)), __fmul_rn(dzB,dzB));
            bool pA = inrv[c] && (d2A <= tauA);
            bool pB = inrv[c] && (d2B <= tauB);
            u64 balA = __ballot(pA);
            u64 balB = __ballot(pB);
            int sorig = 0;
            if (balA | balB) sorig = S[jav[c]];      // wave-uniform: load only when pushing
            if (balA){
                int nins = __popcll(balA);
                if (cntA + nins > QCAP) refine16(bufA, cntA, tauA, lane);
                if (pA){
                    int ofs = __popcll(balA & ((1ull << lane) - 1ull));
                    bufA[cntA + ofs] = (((u64)__float_as_uint(d2A)) << 32) | (u32)sorig;
                }
                cntA += nins;
            }
            if (balB){
                int nins = __popcll(balB);
                if (cntB + nins > QCAP) refine16(bufB, cntB, tauB, lane);
                if (pB){
                    int ofs = __popcll(balB & ((1ull << lane) - 1ull));
                    bufB[cntB + ofs] = (((u64)__float_as_uint(d2B)) << 32) | (u32)sorig;
                }
                cntB += nins;
            }
        }
        // termination from boundary lanes of the last sub-iteration
        // (lane31 = leftmost examined rank, lane63 = rightmost examined rank)
        float xL = __shfl(cxv[3], 31);
        float xR = __shfl(cxv[3], 63);
        const int k = k0 + 3;
        bool lex = (rA - ((k + 1) << 5) - 1) < 0;    // left side exhausted
        bool rex = (rA + ((k + 1) << 5)) >= NN;      // right side exhausted
        float dLa = axq - xL, dRa = xR - axq;
        float dLb = bxq - xL, dRb = xR - bxq;
        bool ldone = lex || (dLa*dLa > tauA && dLb*dLb > tauB);
        bool rdone = rex || (dRa*dRa > tauA && dRb*dRb > tauB);
        if (ldone && rdone) break;
    }
    refine16(bufA, cntA, tauA, lane);
    refine16(bufB, cntB, tauB, lane);
    const int origA = S[rA], origB = S[rB];
    if (lane < KK){
        u64 kA = bufA[lane];
        int jA = (int)(u32)(kA & 0xFFFFFFFFu);
        knn_out[((size_t)(b*NN + origA))*KK + lane] = jA;
        atomicAdd(deg + (b << 12) + jA, 1u);
        u64 kB = bufB[lane];
        int jB = (int)(u32)(kB & 0xFFFFFFFFu);
        knn_out[((size_t)(b*NN + origB))*KK + lane] = jB;
        atomicAdd(deg + (b << 12) + jB, 1u);
    }
}

// ---------------------------------------------------------------- CSR build
__global__ __launch_bounds__(1024) void scan_kernel(const u32* __restrict__ deg,
                                                    int* __restrict__ rowstart, u32* __restrict__ cursor){
    __shared__ int lsum[1024];
    const int tid = threadIdx.x;
    const int base = tid * 16;
    int loc[16]; int s = 0;
    #pragma unroll
    for (int q = 0; q < 16; ++q){ loc[q] = (int)deg[base+q]; s += loc[q]; }
    lsum[tid] = s;
    __syncthreads();
    int acc = s;
    for (int ofs = 1; ofs < 1024; ofs <<= 1){
        int t = (tid >= ofs) ? lsum[tid-ofs] : 0;
        __syncthreads();
        acc += t; lsum[tid] = acc;
        __syncthreads();
    }
    int excl = acc - s;
    #pragma unroll
    for (int q = 0; q < 16; ++q){
        rowstart[base+q] = excl; cursor[base+q] = (u32)excl; excl += loc[q];
    }
    if (tid == 1023) rowstart[16384] = excl;
}

__global__ __launch_bounds__(256) void fill_kernel(const int* __restrict__ knn,
                                                   u32* __restrict__ cursor, int* __restrict__ csr){
    int e = blockIdx.x*256 + threadIdx.x;
    int b = e >> 16;
    int t = (b << 12) + knn[e];
    u32 pos = atomicAdd(cursor + t, 1u);
    csr[pos] = e;
}

// ---------------------------------------------------------------- LDS fragment helpers
__device__ __forceinline__ bf16x8 ldfrag(const u16* h, int row, int kofs, int rowstride){
    u32 byte = (u32)((row*rowstride + kofs)*2) ^ (u32)((row & 7) << 4);
    return *(const bf16x8*)((const char*)h + byte);
}
__device__ __forceinline__ void st16(u16* h, int row, int col, int rowstride, float v){
    u32 byte = (u32)((row*rowstride + col)*2) ^ (u32)((row & 7) << 4);
    *(u16*)((char*)h + byte) = f2b(v);
}

// ---------------------------------------------------------------- edge MLP (MFMA) + segment max
__global__ __launch_bounds__(256, 2) void edge_kernel(
    const float* __restrict__ conv, const int* __restrict__ knn,
    const int* __restrict__ rowstart, const int* __restrict__ csr,
    const u16* __restrict__ wp2, const u16* __restrict__ wp3,
    u16* __restrict__ xh)
{
    __shared__ float in6[6][64];
    __shared__ int   lts[64];
    __shared__ int   rs_l[17];
    __shared__ float scw1[384];
    __shared__ float sc1[64], sh1[64];
    __shared__ __align__(16) u16 h1s[64*64];    // 8 KB swizzled [edge][ch]
    __shared__ __align__(16) u16 h2s[64*128];   // 16 KB swizzled
    __shared__ u32 lsx[16*256];                 // 16 KB fmap-max accumulator [target][ch]

    const float* posf = conv + O_POS;
    const float* cb1 = conv + O_CB1; const float* cg1 = conv + O_CG1; const float* cs1 = conv + O_CS1;

    const int tid = threadIdx.x;
    const int w   = tid >> 6;
    const int l   = tid & 63;
    const int t0  = blockIdx.x << 4;
    const int b   = t0 >> 12;

    if (tid < 64){ float g1 = cg1[tid]; sc1[tid]=g1; sh1[tid]=cb1[tid]*g1 + cs1[tid]; }
    if (tid < 17) rs_l[tid] = rowstart[t0 + tid];
    for (int u = tid; u < 384; u += 256) scw1[u] = conv[O_CW1 + u];
    #pragma unroll
    for (int q = 0; q < 16; ++q) lsx[q*256 + tid] = 0u;   // fmap identity (< any real value)

    const int lr = l & 15, lg = l >> 4;
    const int colb2 = w << 5;          // layer-2 cols [w*32, +32)
    const int colb3 = w << 6;          // layer-3 cols [w*64, +64)

    float sc2v[2], sh2v[2], bs3v[4];
    #pragma unroll
    for (int nt = 0; nt < 2; ++nt){
        int c = colb2 + nt*16 + lr;
        float g2 = conv[O_CG2 + c];
        sc2v[nt] = g2; sh2v[nt] = conv[O_CB2 + c]*g2 + conv[O_CS2 + c];
    }
    #pragma unroll
    for (int nt = 0; nt < 4; ++nt) bs3v[nt] = conv[O_CB3 + colb3 + nt*16 + lr];

    __syncthreads();
    const int segstart = rs_l[0], segend = rs_l[16];
    const int nchunk = (segend - segstart + 63) >> 6;

    int curl = -1;
    float run[4];
    #pragma unroll
    for (int nt = 0; nt < 4; ++nt) run[nt] = 0.f;

    for (int ch = 0; ch < nchunk; ++ch){
        __syncthreads();   // prev chunk's lts/in6/LDS fully consumed
        if (tid < 64){
            int gpos = segstart + (ch << 6) + tid;
            int lt = -1;
            float ax=0,ay=0,az=0,dx=0,dy=0,dz=0;
            if (gpos < segend){
                lt = 0;
                #pragma unroll
                for (int q = 1; q < 16; ++q) lt += (gpos >= rs_l[q]) ? 1 : 0;
                int e = csr[gpos];
                int i = (e >> 4) & (NN - 1);
                int j = knn[e];
                const float* pi = posf + ((size_t)(b*NN + i))*3;
                const float* pj = posf + ((size_t)(b*NN + j))*3;
                ax = pi[0]; ay = pi[1]; az = pi[2];
                dx = ax - pj[0]; dy = ay - pj[1]; dz = az - pj[2];
            }
            lts[tid] = lt;
            in6[0][tid]=ax; in6[1][tid]=ay; in6[2][tid]=az;
            in6[3][tid]=dx; in6[4][tid]=dy; in6[5][tid]=dz;
        }
        __syncthreads();

        { // layer 1 (VALU, K=6): thread -> edge tid&63, channels (tid>>6)*16..+15
            const int e = tid & 63, c0g = (tid >> 6) << 4;
            float a0=in6[0][e], a1=in6[1][e], a2=in6[2][e],
                  a3=in6[3][e], a4=in6[4][e], a5=in6[5][e];
            u32 pk[8];
            #pragma unroll
            for (int ci = 0; ci < 16; ++ci){
                int cc = c0g + ci;
                float acc = a0*scw1[cc]     + a1*scw1[64+cc]  + a2*scw1[128+cc]
                          + a3*scw1[192+cc] + a4*scw1[256+cc] + a5*scw1[320+cc];
                float v = fmaxf(acc*sc1[cc] + sh1[cc], 0.f);
                u32 h = (u32)f2b(v);
                if (ci & 1) pk[ci >> 1] |= h << 16; else pk[ci >> 1] = h;
            }
            u32 base = (u32)(e*128 + c0g*2);
            u32 swz  = (u32)((e & 7) << 4);
            *(uint4*)((char*)h1s + (base ^ swz))        = make_uint4(pk[0],pk[1],pk[2],pk[3]);
            *(uint4*)((char*)h1s + ((base + 16) ^ swz)) = make_uint4(pk[4],pk[5],pk[6],pk[7]);
        }
        __syncthreads();

        { // layer 2 (MFMA): M=64, N=128 (wave: 32 cols), K=64; B streamed
            f32x4 acc2[4][2];
            #pragma unroll
            for (int mt = 0; mt < 4; ++mt)
                #pragma unroll
                for (int nt = 0; nt < 2; ++nt) acc2[mt][nt] = (f32x4){0.f,0.f,0.f,0.f};
            #pragma unroll
            for (int ks = 0; ks < 2; ++ks){
                bf16x8 bf[2];
                #pragma unroll
                for (int nt = 0; nt < 2; ++nt)
                    bf[nt] = *(const bf16x8*)(wp2 + (((ks*128 + colb2 + nt*16 + lr) << 2) + lg)*8);
                #pragma unroll
                for (int mt = 0; mt < 4; ++mt){
                    bf16x8 a = ldfrag(h1s, mt*16 + lr, ks*32 + lg*8, 64);
                    #pragma unroll
                    for (int nt = 0; nt < 2; ++nt)
                        acc2[mt][nt] = __builtin_amdgcn_mfma_f32_16x16x32_bf16(a, bf[nt], acc2[mt][nt], 0, 0, 0);
                }
            }
            #pragma unroll
            for (int mt = 0; mt < 4; ++mt)
                #pragma unroll
                for (int nt = 0; nt < 2; ++nt)
                    #pragma unroll
                    for (int r = 0; r < 4; ++r){
                        int row = mt*16 + lg*4 + r;
                        float v = fmaxf(acc2[mt][nt][r]*sc2v[nt] + sh2v[nt], 0.f);
                        st16(h2s, row, colb2 + nt*16 + lr, 128, v);
                    }
        }
        __syncthreads();

        { // layer 3 (MFMA): M=64, N=256 (wave: 64 cols), K=128; B streamed;
          // segmented max flushed straight from the accumulator into lsx
            f32x4 acc3[4][4];
            #pragma unroll
            for (int mt = 0; mt < 4; ++mt)
                #pragma unroll
                for (int nt = 0; nt < 4; ++nt) acc3[mt][nt] = (f32x4){0.f,0.f,0.f,0.f};
            #pragma unroll
            for (int ks = 0; ks < 4; ++ks){
                bf16x8 bf[4];
                #pragma unroll
                for (int nt = 0; nt < 4; ++nt)
                    bf[nt] = *(const bf16x8*)(wp3 + (((ks*256 + colb3 + nt*16 + lr) << 2) + lg)*8);
                #pragma unroll
                for (int mt = 0; mt < 4; ++mt){
                    bf16x8 a = ldfrag(h2s, mt*16 + lr, ks*32 + lg*8, 128);
                    #pragma unroll
                    for (int nt = 0; nt < 4; ++nt)
                        acc3[mt][nt] = __builtin_amdgcn_mfma_f32_16x16x32_bf16(a, bf[nt], acc3[mt][nt], 0, 0, 0);
                }
            }
            // per-lane run-length segmented max (rows ascend per lane; labels sorted)
            #pragma unroll
            for (int mt = 0; mt < 4; ++mt)
                #pragma unroll
                for (int r = 0; r < 4; ++r){
                    int row = mt*16 + lg*4 + r;
                    int lt = lts[row];
                    if (lt != curl){
                        if (curl >= 0){
                            #pragma unroll
                            for (int nt = 0; nt < 4; ++nt)
                                atomicMax(&lsx[curl*256 + colb3 + nt*16 + lr], fmap(run[nt]));
                        }
                        curl = lt;
                        #pragma unroll
                        for (int nt = 0; nt < 4; ++nt) run[nt] = acc3[mt][nt][r] + bs3v[nt];
                    } else {
                        #pragma unroll
                        for (int nt = 0; nt < 4; ++nt) run[nt] = fmaxf(run[nt], acc3[mt][nt][r] + bs3v[nt]);
                    }
                }
        }
    }
    if (curl >= 0){
        #pragma unroll
        for (int nt = 0; nt < 4; ++nt)
            atomicMax(&lsx[curl*256 + colb3 + nt*16 + lr], fmap(run[nt]));
    }
    __syncthreads();
    #pragma unroll
    for (int q = 0; q < 16; ++q)
        xh[((size_t)(t0+q))*256 + tid] = f2b(funmap(lsx[q*256 + tid]));
}

// ---------------------------------------------------------------- GlobalSA MLP (MFMA) + scene max
__global__ __launch_bounds__(256, 3) void sa_kernel(
    const float* __restrict__ conv, const u16* __restrict__ xh,
    const u16* __restrict__ swp1, const u16* __restrict__ swp2, const u16* __restrict__ swp3,
    u32* __restrict__ scene_map)
{
    __shared__ __align__(16) u16 h1s[32*256];   // 16KB
    __shared__ __align__(16) u16 h2s[32*512];   // 32KB
    __shared__ float spw[3][256];
    __shared__ float spx[32], spy[32], spz[32];

    const int tid = threadIdx.x;
    const int w   = tid >> 6;
    const int l   = tid & 63;
    const int lr  = l & 15, lg = l >> 4;
    const int b   = blockIdx.x >> 7;
    const int n0  = (blockIdx.x & 127) << 5;
    const u16* xrow = xh + ((size_t)(b*NN + n0))*256;

    if (tid < 96){
        int p = tid & 31, d = tid >> 5;
        float v = conv[O_POS + ((size_t)(b*NN + n0 + p))*3 + d];
        if (d == 0) spx[p] = v; else if (d == 1) spy[p] = v; else spz[p] = v;
    }
    for (int u = tid; u < 768; u += 256)
        spw[u >> 8][u & 255] = conv[O_SW1 + (256 + (u >> 8))*256 + (u & 255)];
    __syncthreads();

    { // s1: 259 -> 256 ; wave cols [w*64, +64); A from global xh
        const int c0 = w << 6;
        float sc1v[4], sh1v[4];
        #pragma unroll
        for (int nt = 0; nt < 4; ++nt){
            int cc = c0 + nt*16 + lr;
            float g = conv[O_SG1 + cc];
            sc1v[nt] = g; sh1v[nt] = conv[O_SB1 + cc]*g + conv[O_SS1 + cc];
        }
        f32x4 acc[2][4];
        #pragma unroll
        for (int mt = 0; mt < 2; ++mt)
            #pragma unroll
            for (int nt = 0; nt < 4; ++nt)
                #pragma unroll
                for (int r = 0; r < 4; ++r){
                    int row = mt*16 + lg*4 + r;
                    int cc  = c0 + nt*16 + lr;
                    acc[mt][nt][r] = spx[row]*spw[0][cc] + spy[row]*spw[1][cc] + spz[row]*spw[2][cc];
                }
        #pragma unroll
        for (int ks = 0; ks < 8; ++ks){
            bf16x8 bf[4];
            #pragma unroll
            for (int nt = 0; nt < 4; ++nt)
                bf[nt] = *(const bf16x8*)(swp1 + (((ks*256 + c0 + nt*16 + lr) << 2) + lg)*8);
            #pragma unroll
            for (int mt = 0; mt < 2; ++mt){
                bf16x8 a = *(const bf16x8*)(xrow + (mt*16 + lr)*256 + ks*32 + lg*8);
                #pragma unroll
                for (int nt = 0; nt < 4; ++nt)
                    acc[mt][nt] = __builtin_amdgcn_mfma_f32_16x16x32_bf16(a, bf[nt], acc[mt][nt], 0, 0, 0);
            }
        }
        #pragma unroll
        for (int mt = 0; mt < 2; ++mt)
            #pragma unroll
            for (int nt = 0; nt < 4; ++nt)
                #pragma unroll
                for (int r = 0; r < 4; ++r){
                    int row = mt*16 + lg*4 + r;
                    float v = fmaxf(acc[mt][nt][r]*sc1v[nt] + sh1v[nt], 0.f);
                    st16(h1s, row, c0 + nt*16 + lr, 256, v);
                }
    }
    __syncthreads();

    { // s2: 256 -> 512 ; wave cols [w*128, +128)
        const int c0 = w << 7;
        float sc2v[8], sh2v[8];
        #pragma unroll
        for (int nt = 0; nt < 8; ++nt){
            int cc = c0 + nt*16 + lr;
            float g = conv[O_SG2 + cc];
            sc2v[nt] = g; sh2v[nt] = conv[O_SB2 + cc]*g + conv[O_SS2 + cc];
        }
        f32x4 acc[2][8];
        #pragma unroll
        for (int mt = 0; mt < 2; ++mt)
            #pragma unroll
            for (int nt = 0; nt < 8; ++nt) acc[mt][nt] = (f32x4){0.f,0.f,0.f,0.f};
        #pragma unroll
        for (int ks = 0; ks < 8; ++ks){
            bf16x8 bf[8];
            #pragma unroll
            for (int nt = 0; nt < 8; ++nt)
                bf[nt] = *(const bf16x8*)(swp2 + (((ks*512 + c0 + nt*16 + lr) << 2) + lg)*8);
            #pragma unroll
            for (int mt = 0; mt < 2; ++mt){
                bf16x8 a = ldfrag(h1s, mt*16 + lr, ks*32 + lg*8, 256);
                #pragma unroll
                for (int nt = 0; nt < 8; ++nt)
                    acc[mt][nt] = __builtin_amdgcn_mfma_f32_16x16x32_bf16(a, bf[nt], acc[mt][nt], 0, 0, 0);
            }
        }
        #pragma unroll
        for (int mt = 0; mt < 2; ++mt)
            #pragma unroll
            for (int nt = 0; nt < 8; ++nt)
                #pragma unroll
                for (int r = 0; r < 4; ++r){
                    int row = mt*16 + lg*4 + r;
                    float v = fmaxf(acc[mt][nt][r]*sc2v[nt] + sh2v[nt], 0.f);
                    st16(h2s, row, c0 + nt*16 + lr, 512, v);
                }
    }
    __syncthreads();

    #pragma unroll
    for (int half = 0; half < 2; ++half){
        const int c0 = (half << 9) + (w << 7);
        f32x4 acc[2][8];
        #pragma unroll
        for (int mt = 0; mt < 2; ++mt)
            #pragma unroll
            for (int nt = 0; nt < 8; ++nt) acc[mt][nt] = (f32x4){0.f,0.f,0.f,0.f};
        #pragma unroll
        for (int ks = 0; ks < 16; ++ks){
            bf16x8 bf[8];
            #pragma unroll
            for (int nt = 0; nt < 8; ++nt)
                bf[nt] = *(const bf16x8*)(swp3 + (((ks*1024 + c0 + nt*16 + lr) << 2) + lg)*8);
            #pragma unroll
            for (int mt = 0; mt < 2; ++mt){
                bf16x8 a = ldfrag(h2s, mt*16 + lr, ks*32 + lg*8, 512);
                #pragma unroll
                for (int nt = 0; nt < 8; ++nt)
                    acc[mt][nt] = __builtin_amdgcn_mfma_f32_16x16x32_bf16(a, bf[nt], acc[mt][nt], 0, 0, 0);
            }
        }
        #pragma unroll
        for (int nt = 0; nt < 8; ++nt){
            float v = acc[0][nt][0];
            #pragma unroll
            for (int mt = 0; mt < 2; ++mt)
                #pragma unroll
                for (int r = 0; r < 4; ++r) v = fmaxf(v, acc[mt][nt][r]);
            v = fmaxf(v, __shfl_xor(v, 16));
            v = fmaxf(v, __shfl_xor(v, 32));
            if (lg == 0){
                int cc = c0 + nt*16 + lr;
                atomicMax(scene_map + (b << 10) + cc, fmap(v + conv[O_SB3 + cc]));
            }
        }
    }
}

// ---------------------------------------------------------------- head
__global__ __launch_bounds__(128) void head1_kernel(
    const float* __restrict__ conv,
    const u16* __restrict__ xh, const u32* __restrict__ scene_map, const int* __restrict__ qidx,
    float* __restrict__ h1out)
{
    __shared__ float ef[1280];
    __shared__ float psum[4][32];
    const float* pw1 = conv + O_PW1; const float* pb1 = conv + O_PB1;
    const int b  = blockIdx.x >> 4;
    const int c0 = (blockIdx.x & 15) << 5;
    const int tid = threadIdx.x;
    const int q = qidx[b];
    for (int u = tid; u < 1280; u += 128){
        float v;
        if (u < 256) v = b2f(xh[(((size_t)(b*NN + q)) << 8) + u]);
        else         v = funmap(scene_map[(b << 10) + (u - 256)]);
        ef[u] = v;
    }
    __syncthreads();
    const int c = c0 + (tid & 31);
    const int rc = tid >> 5;
    float acc = 0.f;
    for (int r = rc*320; r < rc*320 + 320; ++r) acc += ef[r] * pw1[r*512 + c];
    psum[rc][tid & 31] = acc;
    __syncthreads();
    if (tid < 32){
        float a = psum[0][tid] + psum[1][tid] + psum[2][tid] + psum[3][tid] + pb1[c0 + tid];
        h1out[(b << 9) + c0 + tid] = fmaxf(a, 0.f);
    }
}

__global__ __launch_bounds__(256) void head2_kernel(
    const float* __restrict__ conv, const float* __restrict__ h1in,
    const u32* __restrict__ flagp, void* __restrict__ outv)
{
    __shared__ float h1[4][512];
    __shared__ float h2[4][256];
    const float* pw2 = conv + O_PW2; const float* pb2 = conv + O_PB2;
    const float* pw3 = conv + O_PW3; const float* pb3 = conv + O_PB3;
    const int tid = threadIdx.x;
    for (int u = tid; u < 2048; u += 256) h1[u >> 9][u & 511] = h1in[u];
    __syncthreads();
    for (int o = tid; o < 1024; o += 256){
        int b = o >> 8, c = o & 255;
        float acc = pb2[c];
        for (int r = 0; r < 512; ++r) acc += h1[b][r] * pw2[r*256 + c];
        h2[b][c] = fmaxf(acc, 0.f);
    }
    __syncthreads();
    if (tid < 64){
        int b = tid >> 4, c = tid & 15;
        float acc = pb3[c];
        for (int r = 0; r < 256; ++r) acc += h2[b][r] * pw3[r*16 + c];
        if (*flagp) ((u16*)outv)[tid] = f2b(acc);
        else        ((float*)outv)[tid] = acc;
    }
}

// ---------------------------------------------------------------- launch
extern "C" void kernel_launch(void* const* d_in, const int* in_sizes, int n_in,
                              void* d_out, int out_size, void* d_ws, size_t ws_size,
                              hipStream_t stream){
    (void)in_sizes; (void)n_in; (void)out_size; (void)ws_size;
    const int* qidx = (const int*)d_in[1];

    char* ws = (char*)d_ws;
    u32*  flag      = (u32*)ws;                       // @0
    float* conv     = (float*)(ws + 1024);            // 6.43 MB f32
    u16*  wp2       = (u16*)(ws + 6432768);           // 16 KB  packed cw2
    u16*  wp3       = (u16*)(ws + 6449152);           // 64 KB  packed cw3
    u16*  swp1      = (u16*)(ws + 6514688);           // 128 KB packed sw1[0:256]
    u16*  swp2      = (u16*)(ws + 6645760);           // 256 KB packed sw2
    u16*  swp3      = (u16*)(ws + 6907904);           // 1 MB   packed sw3
    int*  knn       = (int*)(ws + 7956480);           // 1 MB
    u32*  deg       = (u32*)(ws + 9005056);           // 64 KB
    u32*  scene_map = (u32*)(ws + 9070592);           // 16 KB
    int*  rowstart  = (int*)(ws + 9086976);           // 64 KB + 4
    u32*  cursor    = (u32*)(ws + 9152576);           // 64 KB
    int*  csr       = (int*)(ws + 9218112);           // 1 MB
    u16*  xh        = (u16*)(ws + 10266688);          // 8 MB  [B*N, 256] bf16
    float* h1ws     = (float*)(ws + 18655296);        // 8 KB
    float* psoa     = (float*)(ws + 18663488);        // 192 KB SoA positions [3][B*N]
    float* xs       = (float*)(ws + 18860096);        // 64 KB sorted x
    float* ys       = (float*)(ws + 18925632);        // 64 KB sorted-permuted y
    float* zs       = (float*)(ws + 18991168);        // 64 KB sorted-permuted z
    int*   sidx     = (int*)(ws + 19056704);          // 64 KB sorted -> original idx
    u64*   keys     = (u64*)(ws + 19122240);          // 128 KB stage-1 sorted keys

    Ptrs pt;
    pt.p[0] = d_in[0];
    for (int k = 1; k < N_ARR; ++k) pt.p[k] = d_in[k + 1];

    hipMemsetAsync(ws + 9005056, 0, 81920, stream);   // deg + scene_map

    detect_kernel <<<1, 256, 0, stream>>>((const u16*)d_in[0], flag);
    prep_kernel   <<<512, 256, 0, stream>>>(pt, flag, conv, psoa, wp2, wp3, swp1, swp2, swp3);
    sort1_kernel  <<<BB*2, 1024, 0, stream>>>(psoa, keys);
    sort2_kernel  <<<BB, 1024, 0, stream>>>(keys, psoa, xs, ys, zs, sidx);
    knn_kernel <<<1024, 512, 0, stream>>>(xs, ys, zs, sidx, knn, deg);
    scan_kernel<<<1, 1024, 0, stream>>>(deg, rowstart, cursor);
    fill_kernel<<<1024, 256, 0, stream>>>(knn, cursor, csr);
    edge_kernel<<<1024, 256, 0, stream>>>(conv, knn, rowstart, csr, wp2, wp3, xh);
    sa_kernel  <<<512, 256, 0, stream>>>(conv, xh, swp1, swp2, swp3, scene_map);
    head1_kernel<<<64, 128, 0, stream>>>(conv, xh, scene_map, qidx, h1ws);
    head2_kernel<<<1, 256, 0, stream>>>(conv, h1ws, flag, (void*)d_out);
}

// Round 17
// 366.756 us; speedup vs baseline: 1.1625x; 1.0073x over previous
//
#include <hip/hip_runtime.h>

#define BB 4
#define NN 4096
#define KK 16

typedef unsigned short u16;
typedef unsigned int   u32;
typedef unsigned long long u64;

typedef __attribute__((ext_vector_type(8))) short bf16x8;
typedef __attribute__((ext_vector_type(4))) float f32x4;

__device__ __forceinline__ float b2f(u16 x){ return __uint_as_float(((u32)x) << 16); }
__device__ __forceinline__ u16 f2b(float f){
    u32 u = __float_as_uint(f);
    u32 r = (u + 0x7FFFu + ((u >> 16) & 1u)) >> 16;   // RNE
    return (u16)r;
}
__device__ __forceinline__ u32 fmap(float f){
    u32 u = __float_as_uint(f);
    return (u & 0x80000000u) ? ~u : (u | 0x80000000u);
}
__device__ __forceinline__ float funmap(u32 u){
    u32 v = (u & 0x80000000u) ? (u ^ 0x80000000u) : ~u;
    return __uint_as_float(v);
}

// ---------------- input normalization (runtime dtype detect: f32 vs bf16) ----
#define N_ARR 27
__device__ const int ASZ[N_ARR] = {
    49152, 384, 64, 64, 64, 8192, 128, 128, 128, 32768, 256,
    66304, 256, 256, 256, 131072, 512, 512, 512, 524288, 1024,
    655360, 512, 131072, 256, 4096, 16 };
__device__ const int AOFF[N_ARR] = {
    0, 49152, 49536, 49600, 49664, 49728, 57920, 58048, 58176, 58304, 91072,
    91328, 157632, 157888, 158144, 158400, 289472, 289984, 290496, 291008, 815296,
    816320, 1471680, 1472192, 1603264, 1603520, 1607616 };

struct Ptrs { const void* p[N_ARR]; };

#define O_POS 0
#define O_CW1 49152
#define O_CB1 49536
#define O_CG1 49600
#define O_CS1 49664
#define O_CB2 57920
#define O_CG2 58048
#define O_CS2 58176
#define O_CB3 91072
#define O_SW1 91328
#define O_SB1 157632
#define O_SG1 157888
#define O_SS1 158144
#define O_SB2 289472
#define O_SG2 289984
#define O_SS2 290496
#define O_SB3 815296
#define O_PW1 816320
#define O_PB1 1471680
#define O_PW2 1472192
#define O_PB2 1603264
#define O_PW3 1603520
#define O_PB3 1607616

__global__ void detect_kernel(const u16* __restrict__ pos_u16, u32* __restrict__ flag){
    __shared__ int cnt;
    if (threadIdx.x == 0) cnt = 0;
    __syncthreads();
    int c = 0;
    #pragma unroll
    for (int s = 0; s < 4; ++s){
        u16 u = pos_u16[2*(threadIdx.x*4 + s)];
        int e = (u >> 7) & 0xFF;
        c += (e >= 0x68 && e <= 0x82) ? 1 : 0;
    }
    atomicAdd(&cnt, c);
    __syncthreads();
    if (threadIdx.x == 0) *flag = (cnt >= 512) ? 1u : 0u;   // 1 = bf16 inputs
}

// Pack weight matrix (row-major KxN) from SOURCE (f32 or bf16) into MFMA B-frag order:
// dst[((ks*N + n)*4 + lg)*8 + i] = bf16(W[(ks*32 + lg*8 + i)*N + n])
__device__ __forceinline__ void pack_one_src(const void* __restrict__ src, bool isbf,
                                             u16* __restrict__ dst, int tot, int log2n,
                                             int g, int T){
    const int nmask = (1 << log2n) - 1;
    for (int id = g; id < tot; id += T){
        int i = id & 7, lg = (id >> 3) & 3;
        int rest = id >> 5;
        int n = rest & nmask;
        int ks = rest >> log2n;
        int si = (ks*32 + lg*8 + i) << log2n | n;
        dst[id] = isbf ? ((const u16*)src)[si] : f2b(((const float*)src)[si]);
    }
}

// convert needed arrays to f32, build SoA positions, pack the 5 MFMA weight matrices
__global__ __launch_bounds__(256) void prep_kernel(Ptrs pt, const u32* __restrict__ flagp,
        float* __restrict__ dst, float* __restrict__ psoa,
        u16* __restrict__ wp2, u16* __restrict__ wp3,
        u16* __restrict__ swp1, u16* __restrict__ swp2, u16* __restrict__ swp3){
    const bool isbf = (*flagp != 0);
    const int T = gridDim.x * 256;
    const int g = blockIdx.x * 256 + threadIdx.x;
    #pragma unroll
    for (int a = 0; a < N_ARR; ++a){
        if (a == 5 || a == 9 || a == 15 || a == 19) continue;   // only packed copies used
        const int sz = ASZ[a], off = AOFF[a];
        if (isbf){
            const u16* s = (const u16*)pt.p[a];
            for (int i = g; i < sz; i += T) dst[off + i] = b2f(s[i]);
        } else {
            const float* s = (const float*)pt.p[a];
            for (int i = g; i < sz; i += T) dst[off + i] = s[i];
        }
    }
    for (int i = g; i < BB*NN; i += T){
        float x, y, z;
        if (isbf){
            const u16* s = (const u16*)pt.p[0];
            x = b2f(s[3*i]); y = b2f(s[3*i+1]); z = b2f(s[3*i+2]);
        } else {
            const float* s = (const float*)pt.p[0];
            x = s[3*i]; y = s[3*i+1]; z = s[3*i+2];
        }
        psoa[i] = x; psoa[BB*NN + i] = y; psoa[2*BB*NN + i] = z;
    }
    pack_one_src(pt.p[5],  isbf, wp2,    8192,  7, g, T);
    pack_one_src(pt.p[9],  isbf, wp3,   32768,  8, g, T);
    pack_one_src(pt.p[11], isbf, swp1,  65536,  8, g, T);   // first 256 K-rows of sw1
    pack_one_src(pt.p[15], isbf, swp2, 131072,  9, g, T);
    pack_one_src(pt.p[19], isbf, swp3, 524288, 10, g, T);
}

// ---------------------------------------------------------------- sort by x (two stages)
__global__ __launch_bounds__(1024) void sort1_kernel(const float* __restrict__ psoa,
                                                     u64* __restrict__ keys){
    __shared__ u64 s[2048];   // 16 KB
    const int half = blockIdx.x;       // 0..7
    const int b    = half >> 1;
    const int base = (half & 1) << 11; // 0 or 2048
    const float* px = psoa + b*NN;
    const int tid = threadIdx.x;
    for (int i = tid; i < 2048; i += 1024)
        s[i] = (((u64)fmap(px[base + i])) << 32) | (u32)(base + i);
    __syncthreads();
    for (int ksz = 2; ksz <= 2048; ksz <<= 1){
        for (int jj = ksz >> 1; jj > 0; jj >>= 1){
            int t = tid;
            int i  = ((t & ~(jj-1)) << 1) | (t & (jj-1));
            int ix = i | jj;
            u64 a = s[i], v = s[ix];
            bool up = (((base + i) & ksz) == 0);
            if ((a > v) == up){ s[i] = v; s[ix] = a; }
            __syncthreads();
        }
    }
    for (int i = tid; i < 2048; i += 1024) keys[b*NN + base + i] = s[i];
}

__global__ __launch_bounds__(1024) void sort2_kernel(const u64* __restrict__ keys,
        const float* __restrict__ psoa,
        float* __restrict__ xs, float* __restrict__ ys, float* __restrict__ zs,
        int* __restrict__ sidx){
    __shared__ u64 s[NN];   // 32 KB
    const int b = blockIdx.x;
    const int tid = threadIdx.x;
    for (int i = tid; i < NN; i += 1024) s[i] = keys[b*NN + i];
    __syncthreads();
    for (int jj = NN >> 1; jj > 0; jj >>= 1){
        for (int t = tid; t < NN/2; t += 1024){
            int i  = ((t & ~(jj-1)) << 1) | (t & (jj-1));
            int ix = i | jj;
            u64 a = s[i], v = s[ix];
            if (a > v){ s[i] = v; s[ix] = a; }   // ksz=4096: ascending everywhere
        }
        __syncthreads();
    }
    const float* py = psoa + BB*NN;
    const float* pz = psoa + 2*BB*NN;
    for (int r = tid; r < NN; r += 1024){
        u64 kv = s[r];
        int oi = (int)(u32)(kv & 0xFFFFFFFFu);
        xs[b*NN + r] = funmap((u32)(kv >> 32));
        ys[b*NN + r] = py[b*NN + oi];
        zs[b*NN + r] = pz[b*NN + oi];
        sidx[b*NN + r] = oi;
    }
}

// ---------------------------------------------------------------- kNN (+ degree count)
// Sorted-axis pruned, exact. Superstep of 4 iterations (12 batched loads, one wait);
// push/refine order per k unchanged (bit-identical selection); termination once per
// superstep (superset, exact). 256-thread blocks (8 queries) for finer tail balance.
#define QCAP 192
__device__ __forceinline__ void refine16(u64* __restrict__ buf, int& cnt, float& tau, int lane){
    u64 loc[3];
    #pragma unroll
    for (int q = 0; q < 3; ++q){
        int p = lane + (q << 6);
        loc[q] = (p < cnt) ? buf[p] : ~0ull;
    }
    u64 m = ~0ull;
    #pragma unroll
    for (int r = 0; r < KK; ++r){
        m = loc[0];
        m = loc[1] < m ? loc[1] : m;
        m = loc[2] < m ? loc[2] : m;
        #pragma unroll
        for (int off = 32; off > 0; off >>= 1){
            u64 o = __shfl_xor(m, off);
            m = o < m ? o : m;
        }
        if (lane == r) buf[r] = m;
        #pragma unroll
        for (int q = 0; q < 3; ++q) if (loc[q] == m) loc[q] = ~0ull;
    }
    cnt = KK;
    tau = __uint_as_float((u32)(m >> 32));   // d2 of the 16th smallest
}

__global__ __launch_bounds__(256) void knn_kernel(
        const float* __restrict__ xs, const float* __restrict__ ys,
        const float* __restrict__ zs, const int* __restrict__ sidx,
        int* __restrict__ knn_out, u32* __restrict__ deg){
    __shared__ __align__(16) u64 kbuf[8*QCAP];   // 12 KB
    const int b  = blockIdx.x >> 9;              // 512 blocks per batch
    const int r0 = (blockIdx.x & 511) << 3;      // 8 sorted-rank queries per block
    const float* X = xs + b*NN;
    const float* Y = ys + b*NN;
    const float* Z = zs + b*NN;
    const int*   S = sidx + b*NN;
    const int tid = threadIdx.x;
    const int lane = tid & 63;
    const int wv = tid >> 6;                     // 0..3
    const int rA = r0 + wv*2, rB = rA + 1;
    const float axq = X[rA], ayq = Y[rA], azq = Z[rA];
    const float bxq = X[rB], byq = Y[rB], bzq = Z[rB];
    u64* bufA = kbuf + (wv*2)*QCAP;
    u64* bufB = bufA + QCAP;

    float tauA = 3.0e38f, tauB = 3.0e38f;
    int cntA = 0, cntB = 0;
    for (int k0 = 0; k0 < 128; k0 += 4){
        // batched candidate loads for 4 sub-iterations (12 independent loads, one wait)
        float cxv[4], cyv[4], czv[4];
        int jav[4]; bool inrv[4];
        #pragma unroll
        for (int c = 0; c < 4; ++c){
            int k = k0 + c;
            int j = (lane < 32) ? (rA - 1 - (k << 5) - lane)
                                : (rA + (k << 5) + (lane - 32));
            bool inr = ((u32)j < (u32)NN);
            int ja = inr ? j : rA;
            inrv[c] = inr; jav[c] = ja;
            cxv[c] = X[ja]; cyv[c] = Y[ja]; czv[c] = Z[ja];
        }
        #pragma unroll
        for (int c = 0; c < 4; ++c){
            float cx = cxv[c], cy = cyv[c], cz = czv[c];
            float dxA = axq - cx, dyA = ayq - cy, dzA = azq - cz;
            float d2A = __fadd_rn(__fadd_rn(__fmul_rn(dxA,dxA), __fmul_rn(dyA,dyA)), __fmul_rn(dzA,dzA));
            float dxB = bxq - cx, dyB = byq - cy, dzB = bzq - cz;
            float d2B = __fadd_rn(__fadd_rn(__fmul_rn(dxB,dxB), __fmul_rn(dyB,dyB)), __fmul_rn(dzB,dzB));
            bool pA = inrv[c] && (d2A <= tauA);
            bool pB = inrv[c] && (d2B <= tauB);
            u64 balA = __ballot(pA);
            u64 balB = __ballot(pB);
            int sorig = 0;
            if (balA | balB) sorig = S[jav[c]];      // wave-uniform: load only when pushing
            if (balA){
                int nins = __popcll(balA);
                if (cntA + nins > QCAP) refine16(bufA, cntA, tauA, lane);
                if (pA){
                    int ofs = __popcll(balA & ((1ull << lane) - 1ull));
                    bufA[cntA + ofs] = (((u64)__float_as_uint(d2A)) << 32) | (u32)sorig;
                }
                cntA += nins;
            }
            if (balB){
                int nins = __popcll(balB);
                if (cntB + nins > QCAP) refine16(bufB, cntB, tauB, lane);
                if (pB){
                    int ofs = __popcll(balB & ((1ull << lane) - 1ull));
                    bufB[cntB + ofs] = (((u64)__float_as_uint(d2B)) << 32) | (u32)sorig;
                }
                cntB += nins;
            }
        }
        // termination from boundary lanes of the last sub-iteration
        // (lane31 = leftmost examined rank, lane63 = rightmost examined rank)
        float xL = __shfl(cxv[3], 31);
        float xR = __shfl(cxv[3], 63);
        const int k = k0 + 3;
        bool lex = (rA - ((k + 1) << 5) - 1) < 0;    // left side exhausted
        bool rex = (rA + ((k + 1) << 5)) >= NN;      // right side exhausted
        float dLa = axq - xL, dRa = xR - axq;
        float dLb = bxq - xL, dRb = xR - bxq;
        bool ldone = lex || (dLa*dLa > tauA && dLb*dLb > tauB);
        bool rdone = rex || (dRa*dRa > tauA && dRb*dRb > tauB);
        if (ldone && rdone) break;
    }
    refine16(bufA, cntA, tauA, lane);
    refine16(bufB, cntB, tauB, lane);
    const int origA = S[rA], origB = S[rB];
    if (lane < KK){
        u64 kA = bufA[lane];
        int jA = (int)(u32)(kA & 0xFFFFFFFFu);
        knn_out[((size_t)(b*NN + origA))*KK + lane] = jA;
        atomicAdd(deg + (b << 12) + jA, 1u);
        u64 kB = bufB[lane];
        int jB = (int)(u32)(kB & 0xFFFFFFFFu);
        knn_out[((size_t)(b*NN + origB))*KK + lane] = jB;
        atomicAdd(deg + (b << 12) + jB, 1u);
    }
}

// ---------------------------------------------------------------- CSR build
__global__ __launch_bounds__(1024) void scan_kernel(const u32* __restrict__ deg,
                                                    int* __restrict__ rowstart, u32* __restrict__ cursor){
    __shared__ int lsum[1024];
    const int tid = threadIdx.x;
    const int base = tid * 16;
    int loc[16]; int s = 0;
    #pragma unroll
    for (int q = 0; q < 16; ++q){ loc[q] = (int)deg[base+q]; s += loc[q]; }
    lsum[tid] = s;
    __syncthreads();
    int acc = s;
    for (int ofs = 1; ofs < 1024; ofs <<= 1){
        int t = (tid >= ofs) ? lsum[tid-ofs] : 0;
        __syncthreads();
        acc += t; lsum[tid] = acc;
        __syncthreads();
    }
    int excl = acc - s;
    #pragma unroll
    for (int q = 0; q < 16; ++q){
        rowstart[base+q] = excl; cursor[base+q] = (u32)excl; excl += loc[q];
    }
    if (tid == 1023) rowstart[16384] = excl;
}

__global__ __launch_bounds__(256) void fill_kernel(const int* __restrict__ knn,
                                                   u32* __restrict__ cursor, int* __restrict__ csr){
    int e = blockIdx.x*256 + threadIdx.x;
    int b = e >> 16;
    int t = (b << 12) + knn[e];
    u32 pos = atomicAdd(cursor + t, 1u);
    csr[pos] = e;
}

// ---------------------------------------------------------------- LDS fragment helpers
__device__ __forceinline__ bf16x8 ldfrag(const u16* h, int row, int kofs, int rowstride){
    u32 byte = (u32)((row*rowstride + kofs)*2) ^ (u32)((row & 7) << 4);
    return *(const bf16x8*)((const char*)h + byte);
}
__device__ __forceinline__ void st16(u16* h, int row, int col, int rowstride, float v){
    u32 byte = (u32)((row*rowstride + col)*2) ^ (u32)((row & 7) << 4);
    *(u16*)((char*)h + byte) = f2b(v);
}

// ---------------------------------------------------------------- edge MLP (MFMA) + segment max
__global__ __launch_bounds__(256, 2) void edge_kernel(
    const float* __restrict__ conv, const int* __restrict__ knn,
    const int* __restrict__ rowstart, const int* __restrict__ csr,
    const u16* __restrict__ wp2, const u16* __restrict__ wp3,
    u16* __restrict__ xh)
{
    __shared__ float in6[6][64];
    __shared__ int   lts[64];
    __shared__ int   rs_l[17];
    __shared__ float scw1[384];
    __shared__ float sc1[64], sh1[64];
    __shared__ __align__(16) u16 h1s[64*64];    // 8 KB swizzled [edge][ch]
    __shared__ __align__(16) u16 h2s[64*128];   // 16 KB swizzled
    __shared__ u32 lsx[16*256];                 // 16 KB fmap-max accumulator [target][ch]

    const float* posf = conv + O_POS;
    const float* cb1 = conv + O_CB1; const float* cg1 = conv + O_CG1; const float* cs1 = conv + O_CS1;

    const int tid = threadIdx.x;
    const int w   = tid >> 6;
    const int l   = tid & 63;
    const int t0  = blockIdx.x << 4;
    const int b   = t0 >> 12;

    if (tid < 64){ float g1 = cg1[tid]; sc1[tid]=g1; sh1[tid]=cb1[tid]*g1 + cs1[tid]; }
    if (tid < 17) rs_l[tid] = rowstart[t0 + tid];
    for (int u = tid; u < 384; u += 256) scw1[u] = conv[O_CW1 + u];
    #pragma unroll
    for (int q = 0; q < 16; ++q) lsx[q*256 + tid] = 0u;   // fmap identity (< any real value)

    const int lr = l & 15, lg = l >> 4;
    const int colb2 = w << 5;          // layer-2 cols [w*32, +32)
    const int colb3 = w << 6;          // layer-3 cols [w*64, +64)

    float sc2v[2], sh2v[2], bs3v[4];
    #pragma unroll
    for (int nt = 0; nt < 2; ++nt){
        int c = colb2 + nt*16 + lr;
        float g2 = conv[O_CG2 + c];
        sc2v[nt] = g2; sh2v[nt] = conv[O_CB2 + c]*g2 + conv[O_CS2 + c];
    }
    #pragma unroll
    for (int nt = 0; nt < 4; ++nt) bs3v[nt] = conv[O_CB3 + colb3 + nt*16 + lr];

    __syncthreads();
    const int segstart = rs_l[0], segend = rs_l[16];
    const int nchunk = (segend - segstart + 63) >> 6;

    int curl = -1;
    float run[4];
    #pragma unroll
    for (int nt = 0; nt < 4; ++nt) run[nt] = 0.f;

    for (int ch = 0; ch < nchunk; ++ch){
        __syncthreads();   // prev chunk's lts/in6/LDS fully consumed
        if (tid < 64){
            int gpos = segstart + (ch << 6) + tid;
            int lt = -1;
            float ax=0,ay=0,az=0,dx=0,dy=0,dz=0;
            if (gpos < segend){
                lt = 0;
                #pragma unroll
                for (int q = 1; q < 16; ++q) lt += (gpos >= rs_l[q]) ? 1 : 0;
                int e = csr[gpos];
                int i = (e >> 4) & (NN - 1);
                int j = knn[e];
                const float* pi = posf + ((size_t)(b*NN + i))*3;
                const float* pj = posf + ((size_t)(b*NN + j))*3;
                ax = pi[0]; ay = pi[1]; az = pi[2];
                dx = ax - pj[0]; dy = ay - pj[1]; dz = az - pj[2];
            }
            lts[tid] = lt;
            in6[0][tid]=ax; in6[1][tid]=ay; in6[2][tid]=az;
            in6[3][tid]=dx; in6[4][tid]=dy; in6[5][tid]=dz;
        }
        __syncthreads();

        { // layer 1 (VALU, K=6): thread -> edge tid&63, channels (tid>>6)*16..+15
            const int e = tid & 63, c0g = (tid >> 6) << 4;
            float a0=in6[0][e], a1=in6[1][e], a2=in6[2][e],
                  a3=in6[3][e], a4=in6[4][e], a5=in6[5][e];
            u32 pk[8];
            #pragma unroll
            for (int ci = 0; ci < 16; ++ci){
                int cc = c0g + ci;
                float acc = a0*scw1[cc]     + a1*scw1[64+cc]  + a2*scw1[128+cc]
                          + a3*scw1[192+cc] + a4*scw1[256+cc] + a5*scw1[320+cc];
                float v = fmaxf(acc*sc1[cc] + sh1[cc], 0.f);
                u32 h = (u32)f2b(v);
                if (ci & 1) pk[ci >> 1] |= h << 16; else pk[ci >> 1] = h;
            }
            u32 base = (u32)(e*128 + c0g*2);
            u32 swz  = (u32)((e & 7) << 4);
            *(uint4*)((char*)h1s + (base ^ swz))        = make_uint4(pk[0],pk[1],pk[2],pk[3]);
            *(uint4*)((char*)h1s + ((base + 16) ^ swz)) = make_uint4(pk[4],pk[5],pk[6],pk[7]);
        }
        __syncthreads();

        { // layer 2 (MFMA): M=64, N=128 (wave: 32 cols), K=64; B streamed
            f32x4 acc2[4][2];
            #pragma unroll
            for (int mt = 0; mt < 4; ++mt)
                #pragma unroll
                for (int nt = 0; nt < 2; ++nt) acc2[mt][nt] = (f32x4){0.f,0.f,0.f,0.f};
            #pragma unroll
            for (int ks = 0; ks < 2; ++ks){
                bf16x8 bf[2];
                #pragma unroll
                for (int nt = 0; nt < 2; ++nt)
                    bf[nt] = *(const bf16x8*)(wp2 + (((ks*128 + colb2 + nt*16 + lr) << 2) + lg)*8);
                #pragma unroll
                for (int mt = 0; mt < 4; ++mt){
                    bf16x8 a = ldfrag(h1s, mt*16 + lr, ks*32 + lg*8, 64);
                    #pragma unroll
                    for (int nt = 0; nt < 2; ++nt)
                        acc2[mt][nt] = __builtin_amdgcn_mfma_f32_16x16x32_bf16(a, bf[nt], acc2[mt][nt], 0, 0, 0);
                }
            }
            #pragma unroll
            for (int mt = 0; mt < 4; ++mt)
                #pragma unroll
                for (int nt = 0; nt < 2; ++nt)
                    #pragma unroll
                    for (int r = 0; r < 4; ++r){
                        int row = mt*16 + lg*4 + r;
                        float v = fmaxf(acc2[mt][nt][r]*sc2v[nt] + sh2v[nt], 0.f);
                        st16(h2s, row, colb2 + nt*16 + lr, 128, v);
                    }
        }
        __syncthreads();

        { // layer 3 (MFMA): M=64, N=256 (wave: 64 cols), K=128; B streamed;
          // segmented max flushed straight from the accumulator into lsx
            f32x4 acc3[4][4];
            #pragma unroll
            for (int mt = 0; mt < 4; ++mt)
                #pragma unroll
                for (int nt = 0; nt < 4; ++nt) acc3[mt][nt] = (f32x4){0.f,0.f,0.f,0.f};
            #pragma unroll
            for (int ks = 0; ks < 4; ++ks){
                bf16x8 bf[4];
                #pragma unroll
                for (int nt = 0; nt < 4; ++nt)
                    bf[nt] = *(const bf16x8*)(wp3 + (((ks*256 + colb3 + nt*16 + lr) << 2) + lg)*8);
                #pragma unroll
                for (int mt = 0; mt < 4; ++mt){
                    bf16x8 a = ldfrag(h2s, mt*16 + lr, ks*32 + lg*8, 128);
                    #pragma unroll
                    for (int nt = 0; nt < 4; ++nt)
                        acc3[mt][nt] = __builtin_amdgcn_mfma_f32_16x16x32_bf16(a, bf[nt], acc3[mt][nt], 0, 0, 0);
                }
            }
            // per-lane run-length segmented max (rows ascend per lane; labels sorted)
            #pragma unroll
            for (int mt = 0; mt < 4; ++mt)
                #pragma unroll
                for (int r = 0; r < 4; ++r){
                    int row = mt*16 + lg*4 + r;
                    int lt = lts[row];
                    if (lt != curl){
                        if (curl >= 0){
                            #pragma unroll
                            for (int nt = 0; nt < 4; ++nt)
                                atomicMax(&lsx[curl*256 + colb3 + nt*16 + lr], fmap(run[nt]));
                        }
                        curl = lt;
                        #pragma unroll
                        for (int nt = 0; nt < 4; ++nt) run[nt] = acc3[mt][nt][r] + bs3v[nt];
                    } else {
                        #pragma unroll
                        for (int nt = 0; nt < 4; ++nt) run[nt] = fmaxf(run[nt], acc3[mt][nt][r] + bs3v[nt]);
                    }
                }
        }
    }
    if (curl >= 0){
        #pragma unroll
        for (int nt = 0; nt < 4; ++nt)
            atomicMax(&lsx[curl*256 + colb3 + nt*16 + lr], fmap(run[nt]));
    }
    __syncthreads();
    #pragma unroll
    for (int q = 0; q < 16; ++q)
        xh[((size_t)(t0+q))*256 + tid] = f2b(funmap(lsx[q*256 + tid]));
}

// ---------------------------------------------------------------- GlobalSA MLP (MFMA) + scene max
__global__ __launch_bounds__(256, 3) void sa_kernel(
    const float* __restrict__ conv, const u16* __restrict__ xh,
    const u16* __restrict__ swp1, const u16* __restrict__ swp2, const u16* __restrict__ swp3,
    u32* __restrict__ scene_map)
{
    __shared__ __align__(16) u16 h1s[32*256];   // 16KB
    __shared__ __align__(16) u16 h2s[32*512];   // 32KB
    __shared__ float spw[3][256];
    __shared__ float spx[32], spy[32], spz[32];

    const int tid = threadIdx.x;
    const int w   = tid >> 6;
    const int l   = tid & 63;
    const int lr  = l & 15, lg = l >> 4;
    const int b   = blockIdx.x >> 7;
    const int n0  = (blockIdx.x & 127) << 5;
    const u16* xrow = xh + ((size_t)(b*NN + n0))*256;

    if (tid < 96){
        int p = tid & 31, d = tid >> 5;
        float v = conv[O_POS + ((size_t)(b*NN + n0 + p))*3 + d];
        if (d == 0) spx[p] = v; else if (d == 1) spy[p] = v; else spz[p] = v;
    }
    for (int u = tid; u < 768; u += 256)
        spw[u >> 8][u & 255] = conv[O_SW1 + (256 + (u >> 8))*256 + (u & 255)];
    __syncthreads();

    { // s1: 259 -> 256 ; wave cols [w*64, +64); A from global xh
        const int c0 = w << 6;
        float sc1v[4], sh1v[4];
        #pragma unroll
        for (int nt = 0; nt < 4; ++nt){
            int cc = c0 + nt*16 + lr;
            float g = conv[O_SG1 + cc];
            sc1v[nt] = g; sh1v[nt] = conv[O_SB1 + cc]*g + conv[O_SS1 + cc];
        }
        f32x4 acc[2][4];
        #pragma unroll
        for (int mt = 0; mt < 2; ++mt)
            #pragma unroll
            for (int nt = 0; nt < 4; ++nt)
                #pragma unroll
                for (int r = 0; r < 4; ++r){
                    int row = mt*16 + lg*4 + r;
                    int cc  = c0 + nt*16 + lr;
                    acc[mt][nt][r] = spx[row]*spw[0][cc] + spy[row]*spw[1][cc] + spz[row]*spw[2][cc];
                }
        #pragma unroll
        for (int ks = 0; ks < 8; ++ks){
            bf16x8 bf[4];
            #pragma unroll
            for (int nt = 0; nt < 4; ++nt)
                bf[nt] = *(const bf16x8*)(swp1 + (((ks*256 + c0 + nt*16 + lr) << 2) + lg)*8);
            #pragma unroll
            for (int mt = 0; mt < 2; ++mt){
                bf16x8 a = *(const bf16x8*)(xrow + (mt*16 + lr)*256 + ks*32 + lg*8);
                #pragma unroll
                for (int nt = 0; nt < 4; ++nt)
                    acc[mt][nt] = __builtin_amdgcn_mfma_f32_16x16x32_bf16(a, bf[nt], acc[mt][nt], 0, 0, 0);
            }
        }
        #pragma unroll
        for (int mt = 0; mt < 2; ++mt)
            #pragma unroll
            for (int nt = 0; nt < 4; ++nt)
                #pragma unroll
                for (int r = 0; r < 4; ++r){
                    int row = mt*16 + lg*4 + r;
                    float v = fmaxf(acc[mt][nt][r]*sc1v[nt] + sh1v[nt], 0.f);
                    st16(h1s, row, c0 + nt*16 + lr, 256, v);
                }
    }
    __syncthreads();

    { // s2: 256 -> 512 ; wave cols [w*128, +128)
        const int c0 = w << 7;
        float sc2v[8], sh2v[8];
        #pragma unroll
        for (int nt = 0; nt < 8; ++nt){
            int cc = c0 + nt*16 + lr;
            float g = conv[O_SG2 + cc];
            sc2v[nt] = g; sh2v[nt] = conv[O_SB2 + cc]*g + conv[O_SS2 + cc];
        }
        f32x4 acc[2][8];
        #pragma unroll
        for (int mt = 0; mt < 2; ++mt)
            #pragma unroll
            for (int nt = 0; nt < 8; ++nt) acc[mt][nt] = (f32x4){0.f,0.f,0.f,0.f};
        #pragma unroll
        for (int ks = 0; ks < 8; ++ks){
            bf16x8 bf[8];
            #pragma unroll
            for (int nt = 0; nt < 8; ++nt)
                bf[nt] = *(const bf16x8*)(swp2 + (((ks*512 + c0 + nt*16 + lr) << 2) + lg)*8);
            #pragma unroll
            for (int mt = 0; mt < 2; ++mt){
                bf16x8 a = ldfrag(h1s, mt*16 + lr, ks*32 + lg*8, 256);
                #pragma unroll
                for (int nt = 0; nt < 8; ++nt)
                    acc[mt][nt] = __builtin_amdgcn_mfma_f32_16x16x32_bf16(a, bf[nt], acc[mt][nt], 0, 0, 0);
            }
        }
        #pragma unroll
        for (int mt = 0; mt < 2; ++mt)
            #pragma unroll
            for (int nt = 0; nt < 8; ++nt)
                #pragma unroll
                for (int r = 0; r < 4; ++r){
                    int row = mt*16 + lg*4 + r;
                    float v = fmaxf(acc[mt][nt][r]*sc2v[nt] + sh2v[nt], 0.f);
                    st16(h2s, row, c0 + nt*16 + lr, 512, v);
                }
    }
    __syncthreads();

    #pragma unroll
    for (int half = 0; half < 2; ++half){
        const int c0 = (half << 9) + (w << 7);
        f32x4 acc[2][8];
        #pragma unroll
        for (int mt = 0; mt < 2; ++mt)
            #pragma unroll
            for (int nt = 0; nt < 8; ++nt) acc[mt][nt] = (f32x4){0.f,0.f,0.f,0.f};
        #pragma unroll
        for (int ks = 0; ks < 16; ++ks){
            bf16x8 bf[8];
            #pragma unroll
            for (int nt = 0; nt < 8; ++nt)
                bf[nt] = *(const bf16x8*)(swp3 + (((ks*1024 + c0 + nt*16 + lr) << 2) + lg)*8);
            #pragma unroll
            for (int mt = 0; mt < 2; ++mt){
                bf16x8 a = ldfrag(h2s, mt*16 + lr, ks*32 + lg*8, 512);
                #pragma unroll
                for (int nt = 0; nt < 8; ++nt)
                    acc[mt][nt] = __builtin_amdgcn_mfma_f32_16x16x32_bf16(a, bf[nt], acc[mt][nt], 0, 0, 0);
            }
        }
        #pragma unroll
        for (int nt = 0; nt < 8; ++nt){
            float v = acc[0][nt][0];
            #pragma unroll
            for (int mt = 0; mt < 2; ++mt)
                #pragma unroll
                for (int r = 0; r < 4; ++r) v = fmaxf(v, acc[mt][nt][r]);
            v = fmaxf(v, __shfl_xor(v, 16));
            v = fmaxf(v, __shfl_xor(v, 32));
            if (lg == 0){
                int cc = c0 + nt*16 + lr;
                atomicMax(scene_map + (b << 10) + cc, fmap(v + conv[O_SB3 + cc]));
            }
        }
    }
}

// ---------------------------------------------------------------- head
__global__ __launch_bounds__(128) void head1_kernel(
    const float* __restrict__ conv,
    const u16* __restrict__ xh, const u32* __restrict__ scene_map, const int* __restrict__ qidx,
    float* __restrict__ h1out)
{
    __shared__ float ef[1280];
    __shared__ float psum[4][32];
    const float* pw1 = conv + O_PW1; const float* pb1 = conv + O_PB1;
    const int b  = blockIdx.x >> 4;
    const int c0 = (blockIdx.x & 15) << 5;
    const int tid = threadIdx.x;
    const int q = qidx[b];
    for (int u = tid; u < 1280; u += 128){
        float v;
        if (u < 256) v = b2f(xh[(((size_t)(b*NN + q)) << 8) + u]);
        else         v = funmap(scene_map[(b << 10) + (u - 256)]);
        ef[u] = v;
    }
    __syncthreads();
    const int c = c0 + (tid & 31);
    const int rc = tid >> 5;
    float acc = 0.f;
    for (int r = rc*320; r < rc*320 + 320; ++r) acc += ef[r] * pw1[r*512 + c];
    psum[rc][tid & 31] = acc;
    __syncthreads();
    if (tid < 32){
        float a = psum[0][tid] + psum[1][tid] + psum[2][tid] + psum[3][tid] + pb1[c0 + tid];
        h1out[(b << 9) + c0 + tid] = fmaxf(a, 0.f);
    }
}

__global__ __launch_bounds__(256) void head2_kernel(
    const float* __restrict__ conv, const float* __restrict__ h1in,
    const u32* __restrict__ flagp, void* __restrict__ outv)
{
    __shared__ float h1[4][512];
    __shared__ float h2[4][256];
    const float* pw2 = conv + O_PW2; const float* pb2 = conv + O_PB2;
    const float* pw3 = conv + O_PW3; const float* pb3 = conv + O_PB3;
    const int tid = threadIdx.x;
    for (int u = tid; u < 2048; u += 256) h1[u >> 9][u & 511] = h1in[u];
    __syncthreads();
    for (int o = tid; o < 1024; o += 256){
        int b = o >> 8, c = o & 255;
        float acc = pb2[c];
        for (int r = 0; r < 512; ++r) acc += h1[b][r] * pw2[r*256 + c];
        h2[b][c] = fmaxf(acc, 0.f);
    }
    __syncthreads();
    if (tid < 64){
        int b = tid >> 4, c = tid & 15;
        float acc = pb3[c];
        for (int r = 0; r < 256; ++r) acc += h2[b][r] * pw3[r*16 + c];
        if (*flagp) ((u16*)outv)[tid] = f2b(acc);
        else        ((float*)outv)[tid] = acc;
    }
}

// ---------------------------------------------------------------- launch
extern "C" void kernel_launch(void* const* d_in, const int* in_sizes, int n_in,
                              void* d_out, int out_size, void* d_ws, size_t ws_size,
                              hipStream_t stream){
    (void)in_sizes; (void)n_in; (void)out_size; (void)ws_size;
    const int* qidx = (const int*)d_in[1];

    char* ws = (char*)d_ws;
    u32*  flag      = (u32*)ws;                       // @0
    float* conv     = (float*)(ws + 1024);            // 6.43 MB f32
    u16*  wp2       = (u16*)(ws + 6432768);           // 16 KB  packed cw2
    u16*  wp3       = (u16*)(ws + 6449152);           // 64 KB  packed cw3
    u16*  swp1      = (u16*)(ws + 6514688);           // 128 KB packed sw1[0:256]
    u16*  swp2      = (u16*)(ws + 6645760);           // 256 KB packed sw2
    u16*  swp3      = (u16*)(ws + 6907904);           // 1 MB   packed sw3
    int*  knn       = (int*)(ws + 7956480);           // 1 MB
    u32*  deg       = (u32*)(ws + 9005056);           // 64 KB
    u32*  scene_map = (u32*)(ws + 9070592);           // 16 KB
    int*  rowstart  = (int*)(ws + 9086976);           // 64 KB + 4
    u32*  cursor    = (u32*)(ws + 9152576);           // 64 KB
    int*  csr       = (int*)(ws + 9218112);           // 1 MB
    u16*  xh        = (u16*)(ws + 10266688);          // 8 MB  [B*N, 256] bf16
    float* h1ws     = (float*)(ws + 18655296);        // 8 KB
    float* psoa     = (float*)(ws + 18663488);        // 192 KB SoA positions [3][B*N]
    float* xs       = (float*)(ws + 18860096);        // 64 KB sorted x
    float* ys       = (float*)(ws + 18925632);        // 64 KB sorted-permuted y
    float* zs       = (float*)(ws + 18991168);        // 64 KB sorted-permuted z
    int*   sidx     = (int*)(ws + 19056704);          // 64 KB sorted -> original idx
    u64*   keys     = (u64*)(ws + 19122240);          // 128 KB stage-1 sorted keys

    Ptrs pt;
    pt.p[0] = d_in[0];
    for (int k = 1; k < N_ARR; ++k) pt.p[k] = d_in[k + 1];

    hipMemsetAsync(ws + 9005056, 0, 81920, stream);   // deg + scene_map

    detect_kernel <<<1, 256, 0, stream>>>((const u16*)d_in[0], flag);
    prep_kernel   <<<512, 256, 0, stream>>>(pt, flag, conv, psoa, wp2, wp3, swp1, swp2, swp3);
    sort1_kernel  <<<BB*2, 1024, 0, stream>>>(psoa, keys);
    sort2_kernel  <<<BB, 1024, 0, stream>>>(keys, psoa, xs, ys, zs, sidx);
    knn_kernel <<<2048, 256, 0, stream>>>(xs, ys, zs, sidx, knn, deg);
    scan_kernel<<<1, 1024, 0, stream>>>(deg, rowstart, cursor);
    fill_kernel<<<1024, 256, 0, stream>>>(knn, cursor, csr);
    edge_kernel<<<1024, 256, 0, stream>>>(conv, knn, rowstart, csr, wp2, wp3, xh);
    sa_kernel  <<<512, 256, 0, stream>>>(conv, xh, swp1, swp2, swp3, scene_map);
    head1_kernel<<<64, 128, 0, stream>>>(conv, xh, scene_map, qidx, h1ws);
    head2_kernel<<<1, 256, 0, stream>>>(conv, h1ws, flag, (void*)d_out);
}